// Round 6
// baseline (369.161 us; speedup 1.0000x reference)
//
#include <hip/hip_runtime.h>
#include <hip/hip_bf16.h>

typedef __attribute__((ext_vector_type(4))) float f32x4;
typedef __attribute__((ext_vector_type(8))) short s16x8;
typedef __attribute__((ext_vector_type(4))) short s16x4;

#define DEVINL __device__ __forceinline__

static constexpr int BB = 32, TT = 1024, DD = 512, EE = 256, VV = 50257, EXTRA = 200;
static constexpr int D2 = 1024;           // 2*D
static constexpr int VE = VV + EXTRA;     // 50457
static constexpr long MM = (long)BB * TT; // 32768

DEVINL unsigned short f2bf(float x) {
    union { float f; unsigned int u; } c; c.f = x;
    unsigned int u = c.u;
    u += 0x7fffu + ((u >> 16) & 1u);   // round-to-nearest-even
    return (unsigned short)(u >> 16);
}
DEVINL float bf2f(unsigned short h) {
    union { unsigned int u; float f; } c; c.u = ((unsigned int)h) << 16;
    return c.f;
}
DEVINL float sigmoidf_(float x) { return 1.0f / (1.0f + __expf(-x)); }
DEVINL float tanh_fast(float x) {
    x = fminf(15.f, fmaxf(-15.f, x));
    float e = __expf(2.f * x);
    return (e - 1.f) / (e + 1.f);
}
DEVINL void gl16(const void* g, void* l) {  // 16B global->LDS direct (dest: wave base + lane*16)
    __builtin_amdgcn_global_load_lds((__attribute__((address_space(1))) void*)g,
                                     (__attribute__((address_space(3))) void*)l, 16, 0, 0);
}

// ---------------------------------------------------------------- K0: W_h^T -> bf16, k-swizzled
// whtswz[n][k] = bf16(Wh[k ^ ((n&7)<<3)][n])
__global__ void k_transpose_wh(const float* __restrict__ Wh, unsigned short* __restrict__ WhT) {
    __shared__ float tile[32][33];
    int n0 = blockIdx.x * 32, k0 = blockIdx.y * 32;
    int tx = threadIdx.x, ty = threadIdx.y;  // 32 x 8
    #pragma unroll
    for (int i = 0; i < 4; i++)
        tile[ty + i * 8][tx] = Wh[(long)(k0 + ty + i * 8) * D2 + n0 + tx];
    __syncthreads();
    #pragma unroll
    for (int i = 0; i < 4; i++) {
        int n = n0 + ty + i * 8;
        int kcol = (k0 + tx) ^ ((n & 7) << 3);
        WhT[(long)n * D2 + kcol] = f2bf(tile[tx][ty + i * 8]);
    }
}

// ---------------------------------------------------------------- K0b: enc f32 -> bf16, k-swizzled
// encswz[m][k] = bf16(enc[m][k ^ ((m&7)<<3)])
__global__ void k_enc2bf(const float* __restrict__ enc, unsigned short* __restrict__ dst) {
    long idx = (long)blockIdx.x * 256 + threadIdx.x;  // 16384 blocks
    int m  = (int)(idx >> 7);
    int k2 = (int)(idx & 127) * 8;
    int s  = (m & 7) << 3;
    const float* src = enc + (long)m * 1024 + (k2 ^ s);
    f32x4 a = *(const f32x4*)src;
    f32x4 b = *(const f32x4*)(src + 4);
    s16x8 h;
    h[0] = (short)f2bf(a[0]); h[1] = (short)f2bf(a[1]); h[2] = (short)f2bf(a[2]); h[3] = (short)f2bf(a[3]);
    h[4] = (short)f2bf(b[0]); h[5] = (short)f2bf(b[1]); h[6] = (short)f2bf(b[2]); h[7] = (short)f2bf(b[3]);
    *(s16x8*)(dst + (long)m * 1024 + k2) = h;
}

// ---------------------------------------------------------------- K1: x = [pcv|emb] @ W_gx + b_gx
__global__ __launch_bounds__(512) void k_x(
    const int* __restrict__ dec_in, const float* __restrict__ pcv,
    const float* __restrict__ embt, const float* __restrict__ Wgx,
    const float* __restrict__ bgx, float* __restrict__ xbuf) {
    __shared__ float xs[1280];
    __shared__ float sred[8][64];
    int b = blockIdx.x, n0 = blockIdx.y * 64;     // grid (32,4)
    int tid = threadIdx.x, nl = tid & 63, ks = tid >> 6;   // 8 k-slices x 160
    long er = (long)dec_in[b] * EE;
    for (int i = tid; i < 1280; i += 512)
        xs[i] = (i < 1024) ? pcv[b * 1024 + i] : embt[er + i - 1024];
    __syncthreads();
    float acc = 0.f;
    for (int k = ks * 160; k < ks * 160 + 160; ++k)
        acc += xs[k] * Wgx[(long)k * EE + n0 + nl];
    sred[ks][nl] = acc;
    __syncthreads();
    if (tid < 64) {
        int n = n0 + tid;
        float s = bgx[n];
        #pragma unroll
        for (int i = 0; i < 8; i++) s += sred[i][tid];
        xbuf[b * EE + n] = s;
    }
}

// ---------------------------------------------------------------- K2: LSTM cell (fused k-split)
__global__ __launch_bounds__(512) void k_lstm(
    const float* __restrict__ xbuf, const float* __restrict__ h0,
    const float* __restrict__ c0, const float* __restrict__ Wih,
    const float* __restrict__ Whh, const float* __restrict__ bih,
    const float* __restrict__ bhh, float* __restrict__ h1o,
    float* __restrict__ c1o, float* __restrict__ dechat) {
    __shared__ float xs[768];
    __shared__ float sred[4][8][64];
    int b = blockIdx.x, d0 = blockIdx.y * 64;     // grid (32,8)
    int tid = threadIdx.x, dl = tid & 63, ks = tid >> 6;   // 8 k-slices x 96
    for (int i = tid; i < 768; i += 512)
        xs[i] = (i < 256) ? xbuf[b * 256 + i] : h0[b * 512 + i - 256];
    __syncthreads();
    float a0 = 0, a1 = 0, a2 = 0, a3 = 0;
    for (int k = ks * 96; k < ks * 96 + 96; ++k) {
        float xv = xs[k];
        const float* wr = (k < 256) ? (Wih + (long)k * 2048) : (Whh + (long)(k - 256) * 2048);
        a0 += xv * wr[d0 + dl];        a1 += xv * wr[512 + d0 + dl];
        a2 += xv * wr[1024 + d0 + dl]; a3 += xv * wr[1536 + d0 + dl];
    }
    sred[0][ks][dl] = a0; sred[1][ks][dl] = a1; sred[2][ks][dl] = a2; sred[3][ks][dl] = a3;
    __syncthreads();
    if (tid < 64) {
        int d = d0 + tid;
        float gi = bih[d] + bhh[d];
        float gf = bih[512 + d] + bhh[512 + d];
        float gg = bih[1024 + d] + bhh[1024 + d];
        float go = bih[1536 + d] + bhh[1536 + d];
        #pragma unroll
        for (int s = 0; s < 8; s++) {
            gi += sred[0][s][tid]; gf += sred[1][s][tid];
            gg += sred[2][s][tid]; go += sred[3][s][tid];
        }
        float c1 = sigmoidf_(gf) * c0[b * 512 + d] + sigmoidf_(gi) * tanh_fast(gg);
        float h1 = sigmoidf_(go) * tanh_fast(c1);
        h1o[b * 512 + d] = h1; c1o[b * 512 + d] = c1;
        dechat[b * 1024 + d] = h1; dechat[b * 1024 + 512 + d] = c1;
    }
}

// ---------------------------------------------------------------- K3: dec_feat = dec_hat @ W_s + b_s
__global__ __launch_bounds__(512) void k_decfeat(
    const float* __restrict__ dechat, const float* __restrict__ Ws,
    const float* __restrict__ bs, float* __restrict__ decfeat) {
    __shared__ float xs[1024];
    __shared__ float sred[8][64];
    int b = blockIdx.x, n0 = blockIdx.y * 64;     // grid (32,16)
    int tid = threadIdx.x, nl = tid & 63, ks = tid >> 6;   // 8 x 128
    for (int i = tid; i < 1024; i += 512) xs[i] = dechat[b * 1024 + i];
    __syncthreads();
    float acc = 0.f;
    for (int k = ks * 128; k < ks * 128 + 128; ++k)
        acc += xs[k] * Ws[(long)k * 1024 + n0 + nl];
    sred[ks][nl] = acc;
    __syncthreads();
    if (tid < 64) {
        int n = n0 + tid;
        float s = bs[n];
        #pragma unroll
        for (int i = 0; i < 8; i++) s += sred[i][tid];
        decfeat[b * 1024 + n] = s;
    }
}

// ---------------------------------------------------------------- K4: fused attention scores (R2 structure)
__global__ __launch_bounds__(512) void k_scores(
    const unsigned short* __restrict__ encswz, const unsigned short* __restrict__ whtswz,
    const float* __restrict__ decfeat, const float* __restrict__ cov,
    const float* __restrict__ Wc, const float* __restrict__ vvec,
    float* __restrict__ scorep) {
    __shared__ __align__(16) unsigned short As[128 * 64];   // 16 KB, linear, data pre-swizzled
    __shared__ __align__(16) unsigned short Bs[256 * 64];   // 32 KB
    __shared__ float sred[4][128];                          // total 50 KB -> 3 blocks/CU
    const int tid = threadIdx.x;
    const int lane = tid & 63, wave = tid >> 6;
    const int wid = __builtin_amdgcn_readfirstlane(wave);
    const int g = lane >> 4, c = lane & 15;
    const int wm = wave >> 2, wn = wave & 3;   // 2 x 4 waves over 128m x 256n

    const int bid = blockIdx.x;
    const int xcd = bid & 7, t = bid >> 3;
    const int mt = xcd * 32 + (t >> 2), nt = t & 3;
    const long m0 = (long)mt * 128;
    const int n0 = nt * 256;
    const int bblk = mt >> 3;                  // batch row

    const int arow = wid * 16 + (lane >> 3);
    const int axo  = (lane & 7) * 8;
    const int brow = wid * 32 + (lane >> 3);
    unsigned short* aBase = &As[wid * 1024];
    unsigned short* bBase = &Bs[wid * 2048];

    f32x4 acc[4][4];
    #pragma unroll
    for (int i = 0; i < 4; i++)
        #pragma unroll
        for (int j = 0; j < 4; j++) acc[i][j] = (f32x4){0.f, 0.f, 0.f, 0.f};

    const int sx = (c & 7) << 3;               // read-side swizzle

    for (int kt = 0; kt < 16; ++kt) {
        const int k0 = kt * 64;
        __syncthreads();
        gl16(encswz + (m0 + arow) * 1024 + k0 + axo,       aBase);
        gl16(encswz + (m0 + arow + 8) * 1024 + k0 + axo,   aBase + 512);
        gl16(whtswz + (long)(n0 + brow) * 1024 + k0 + axo,        bBase);
        gl16(whtswz + (long)(n0 + brow + 8) * 1024 + k0 + axo,    bBase + 512);
        gl16(whtswz + (long)(n0 + brow + 16) * 1024 + k0 + axo,   bBase + 1024);
        gl16(whtswz + (long)(n0 + brow + 24) * 1024 + k0 + axo,   bBase + 1536);
        __syncthreads();                       // drains vmcnt(0)
        #pragma unroll
        for (int kk = 0; kk < 2; ++kk) {
            const int kse = (kk * 32 + g * 8) ^ sx;
            s16x8 af[4], bfj[4];
            #pragma unroll
            for (int i = 0; i < 4; i++) af[i] = *(const s16x8*)&As[(wm * 64 + i * 16 + c) * 64 + kse];
            #pragma unroll
            for (int j = 0; j < 4; j++) bfj[j] = *(const s16x8*)&Bs[(wn * 64 + j * 16 + c) * 64 + kse];
            #pragma unroll
            for (int i = 0; i < 4; i++)
                #pragma unroll
                for (int j = 0; j < 4; j++)
                    acc[i][j] = __builtin_amdgcn_mfma_f32_16x16x32_bf16(af[i], bfj[j], acc[i][j], 0, 0, 0);
        }
    }
    float dfv[4], wcv[4], vvj[4];
    #pragma unroll
    for (int j = 0; j < 4; j++) {
        int col = n0 + wn * 64 + j * 16 + c;
        dfv[j] = decfeat[bblk * D2 + col];
        wcv[j] = Wc[col];
        vvj[j] = vvec[col];
    }
    float sAcc[4][4];
    #pragma unroll
    for (int i = 0; i < 4; i++) {
        #pragma unroll
        for (int r = 0; r < 4; r++) {
            const long m = m0 + wm * 64 + i * 16 + g * 4 + r;
            const float covm = cov[m];
            float su = 0.f;
            #pragma unroll
            for (int j = 0; j < 4; j++) {
                float e = acc[i][j][r] + dfv[j] + covm * wcv[j];
                su += tanh_fast(e) * vvj[j];
            }
            su += __shfl_xor(su, 1); su += __shfl_xor(su, 2);
            su += __shfl_xor(su, 4); su += __shfl_xor(su, 8);
            sAcc[i][r] = su;
        }
    }
    if (c == 0) {
        #pragma unroll
        for (int i = 0; i < 4; i++)
            #pragma unroll
            for (int r = 0; r < 4; r++)
                sred[wn][wm * 64 + i * 16 + g * 4 + r] = sAcc[i][r];
    }
    __syncthreads();
    if (tid < 128)
        scorep[(long)nt * MM + m0 + tid] = sred[0][tid] + sred[1][tid] + sred[2][tid] + sred[3][tid];
}

// ---------------------------------------------------------------- K5: softmax + mask renorm
__global__ void k_softmax(const float* __restrict__ scorep, const float* __restrict__ mask,
                          const float* __restrict__ cov, float* __restrict__ att,
                          float* __restrict__ covn) {
    int b = blockIdx.x, tid = threadIdx.x;  // 256 threads
    __shared__ float sm[8];
    float sv[4];
    float mx = -1e30f;
    #pragma unroll
    for (int i = 0; i < 4; i++) {
        long idx = (long)b * TT + tid + 256 * i;
        sv[i] = scorep[idx] + scorep[MM + idx] + scorep[2 * MM + idx] + scorep[3 * MM + idx];
        mx = fmaxf(mx, sv[i]);
    }
    for (int o = 32; o; o >>= 1) mx = fmaxf(mx, __shfl_xor(mx, o));
    if ((tid & 63) == 0) sm[tid >> 6] = mx;
    __syncthreads();
    mx = fmaxf(fmaxf(sm[0], sm[1]), fmaxf(sm[2], sm[3]));
    __syncthreads();
    float e[4]; float s = 0.f;
    #pragma unroll
    for (int i = 0; i < 4; i++) { e[i] = __expf(sv[i] - mx); s += e[i]; }
    for (int o = 32; o; o >>= 1) s += __shfl_xor(s, o);
    if ((tid & 63) == 0) sm[tid >> 6] = s;
    __syncthreads();
    s = sm[0] + sm[1] + sm[2] + sm[3];
    __syncthreads();
    float inv = 1.f / s;
    float am[4]; float s2 = 0.f;
    #pragma unroll
    for (int i = 0; i < 4; i++) { am[i] = e[i] * inv * mask[b * TT + tid + 256 * i]; s2 += am[i]; }
    for (int o = 32; o; o >>= 1) s2 += __shfl_xor(s2, o);
    if ((tid & 63) == 0) sm[tid >> 6] = s2;
    __syncthreads();
    s2 = sm[0] + sm[1] + sm[2] + sm[3];
    float inv2 = 1.f / s2;
    #pragma unroll
    for (int i = 0; i < 4; i++) {
        int t = tid + 256 * i;
        float a = am[i] * inv2;
        att[b * TT + t] = a;
        covn[b * TT + t] = cov[b * TT + t] + a;
    }
}

// ---------------------------------------------------------------- K6: context partials (bf16 enc) + reduce
__global__ void k_context(const unsigned short* __restrict__ encswz, const float* __restrict__ att,
                          float* __restrict__ part) {
    int b = blockIdx.x, tc = blockIdx.y;  // grid (32,16)
    int d4 = threadIdx.x;                 // 256 threads -> d = d4*4
    float a0 = 0, a1 = 0, a2 = 0, a3 = 0;
    const float* ab = att + b * TT;
    for (int t = tc * 64; t < tc * 64 + 64; ++t) {
        float a = ab[t];
        int sx = (t & 7) << 3;
        const unsigned short* ep = encswz + ((long)b * TT + t) * D2 + ((d4 * 4) ^ sx);
        s16x4 ev = *(const s16x4*)ep;
        a0 += a * bf2f((unsigned short)ev[0]); a1 += a * bf2f((unsigned short)ev[1]);
        a2 += a * bf2f((unsigned short)ev[2]); a3 += a * bf2f((unsigned short)ev[3]);
    }
    float* pp = part + (long)tc * BB * D2 + b * D2 + d4 * 4;
    pp[0] = a0; pp[1] = a1; pp[2] = a2; pp[3] = a3;
}

__global__ void k_ctxreduce(const float* __restrict__ part, float* __restrict__ ctx) {
    int i = blockIdx.x * 256 + threadIdx.x;  // 128 blocks
    float s = 0.f;
    #pragma unroll
    for (int p = 0; p < 16; p++) s += part[(long)p * BB * D2 + i];
    ctx[i] = s;
}

// ---------------------------------------------------------------- K7a: p_gen
__global__ void k_pgen(const float* __restrict__ ctx, const float* __restrict__ dechat,
                       const float* __restrict__ xbuf, const float* __restrict__ Wpg,
                       const float* __restrict__ bpg, float* __restrict__ pgen) {
    int b = blockIdx.x, tid = threadIdx.x;  // 256 threads
    __shared__ float sm[8];
    float acc = 0.f;
    for (int k = tid; k < D2; k += 256)
        acc += ctx[b * D2 + k] * Wpg[k] + dechat[b * D2 + k] * Wpg[D2 + k];
    acc += xbuf[b * EE + tid] * Wpg[2 * D2 + tid];
    for (int o = 32; o; o >>= 1) acc += __shfl_xor(acc, o);
    if ((tid & 63) == 0) sm[tid >> 6] = acc;
    __syncthreads();
    if (tid == 0) {
        float t = sm[0] + sm[1] + sm[2] + sm[3];
        pgen[b] = sigmoidf_(t + bpg[0]);
    }
}

// ---------------------------------------------------------------- K7b: hiddenT = ([h1|ctx] @ W_v1 + b_v1)^T
__global__ __launch_bounds__(512) void k_hidden(
    const float* __restrict__ h1, const float* __restrict__ ctx,
    const float* __restrict__ Wv1, const float* __restrict__ bv1,
    float* __restrict__ hiddenT) {
    __shared__ float xs[1536];
    __shared__ float sred[8][64];
    int b = blockIdx.x, n0 = blockIdx.y * 64;   // grid (32,8)
    int tid = threadIdx.x, nl = tid & 63, ks = tid >> 6;   // 8 x 192
    for (int i = tid; i < 1536; i += 512)
        xs[i] = (i < 512) ? h1[b * 512 + i] : ctx[b * 1024 + i - 512];
    __syncthreads();
    float acc = 0.f;
    for (int k = ks * 192; k < ks * 192 + 192; ++k)
        acc += xs[k] * Wv1[(long)k * 512 + n0 + nl];
    sred[ks][nl] = acc;
    __syncthreads();
    if (tid < 64) {
        int n = n0 + tid;
        float s = bv1[n];
        #pragma unroll
        for (int i = 0; i < 8; i++) s += sred[i][tid];
        hiddenT[n * 32 + b] = s;       // [k][b] layout for k_logits s_load path
    }
}

// ---------------------------------------------------------------- K8: logits = hidden @ W_v2 + b_v2
// 256 thr = 4 waves; wave w covers k in [w*128, w*128+128) for the block's 64 v-cols.
// acc[32] in VGPRs, hiddenT via block-uniform s_load, LDS cross-wave reduce.
__global__ __launch_bounds__(256) void k_logits(const float* __restrict__ hiddenT,
                                                const float* __restrict__ Wv2,
                                                const float* __restrict__ bv2,
                                                float* __restrict__ logits) {
    __shared__ float red[4][32][64];   // 32 KB
    int tid = threadIdx.x;
    int lane = tid & 63, w = tid >> 6;
    int v = blockIdx.x * 64 + lane;
    int vs = (v < VV) ? v : (VV - 1);  // safe address for loads
    float acc[32];
    #pragma unroll
    for (int i = 0; i < 32; i++) acc[i] = 0.f;
    const float* wp = Wv2 + vs;
    const int k0 = w * 128;
    #pragma unroll 8
    for (int kk = 0; kk < 128; ++kk) {
        int k = k0 + kk;
        float wv = wp[(long)k * VV];
        const float* h = hiddenT + k * 32;   // block-uniform -> s_load
        #pragma unroll
        for (int b = 0; b < 32; b++) acc[b] += h[b] * wv;
    }
    #pragma unroll
    for (int b = 0; b < 32; b++) red[w][b][lane] = acc[b];
    __syncthreads();
    // 256 threads: each writes 8 (b, v) outputs; lanes -> consecutive v (coalesced)
    int vl = tid & 63, bg = (tid >> 6) * 8;
    int vo = blockIdx.x * 64 + vl;
    if (vo < VV) {
        float bvv = bv2[vo];
        #pragma unroll
        for (int i = 0; i < 8; i++) {
            int b = bg + i;
            float s = red[0][b][vl] + red[1][b][vl] + red[2][b][vl] + red[3][b][vl] + bvv;
            logits[(long)b * VV + vo] = s;
        }
    }
}

// ---------------------------------------------------------------- K9: fused rowstats + vocab_final + scatter
__global__ __launch_bounds__(1024) void k_vocab_all(
    const float* __restrict__ logits, const float* __restrict__ pgen,
    const float* __restrict__ extraz, const float* __restrict__ att,
    const int* __restrict__ eiv, float* __restrict__ out0) {
    int b = blockIdx.x, tid = threadIdx.x;   // 32 blocks x 1024 thr
    __shared__ float sm[16];
    const float* lr = logits + (long)b * VV;
    float mx = -1e30f;
    for (int v = tid; v < VV; v += 1024) mx = fmaxf(mx, lr[v]);
    for (int o = 32; o; o >>= 1) mx = fmaxf(mx, __shfl_xor(mx, o));
    if ((tid & 63) == 0) sm[tid >> 6] = mx;
    __syncthreads();
    #pragma unroll
    for (int i = 0; i < 16; i++) mx = fmaxf(mx, sm[i]);
    __syncthreads();
    float s = 0.f;
    for (int v = tid; v < VV; v += 1024) s += __expf(lr[v] - mx);
    for (int o = 32; o; o >>= 1) s += __shfl_xor(s, o);
    if ((tid & 63) == 0) sm[tid >> 6] = s;
    __syncthreads();
    s = 0.f;
    #pragma unroll
    for (int i = 0; i < 16; i++) s += sm[i];
    float pg = pgen[b];
    float inv = pg / s;
    float* orow = out0 + (long)b * VE;
    for (int v = tid; v < VV; v += 1024) orow[v] = __expf(lr[v] - mx) * inv;
    if (tid < EXTRA) orow[VV + tid] = extraz[b * EXTRA + tid];
    __syncthreads();
    float a = (1.f - pg) * att[b * TT + tid];
    atomicAdd(orow + eiv[b * TT + tid], a);
}

// ================================================================ host
extern "C" void kernel_launch(void* const* d_in, const int* in_sizes, int n_in,
                              void* d_out, int out_size, void* d_ws, size_t ws_size,
                              hipStream_t stream) {
    const int*   dec_in = (const int*)d_in[0];
    const float* h0     = (const float*)d_in[1];
    const float* c0     = (const float*)d_in[2];
    const float* enc    = (const float*)d_in[3];
    const float* mask   = (const float*)d_in[4];
    const float* pcv    = (const float*)d_in[5];
    const float* cov    = (const float*)d_in[6];
    const float* extraz = (const float*)d_in[7];
    const int*   eiv    = (const int*)d_in[8];
    /* d_in[9] = step (unused, training path) */
    const float* embt   = (const float*)d_in[10];
    const float* Wgx    = (const float*)d_in[11];
    const float* bgx    = (const float*)d_in[12];
    const float* Wih    = (const float*)d_in[13];
    const float* Whh    = (const float*)d_in[14];
    const float* bih    = (const float*)d_in[15];
    const float* bhh    = (const float*)d_in[16];
    const float* Wh     = (const float*)d_in[17];
    const float* Wc     = (const float*)d_in[18];
    const float* Ws     = (const float*)d_in[19];
    const float* bs     = (const float*)d_in[20];
    const float* vv     = (const float*)d_in[21];
    const float* Wpg    = (const float*)d_in[22];
    const float* bpg    = (const float*)d_in[23];
    const float* Wv1    = (const float*)d_in[24];
    const float* bv1    = (const float*)d_in[25];
    const float* Wv2    = (const float*)d_in[26];
    const float* bv2    = (const float*)d_in[27];

    float* out = (float*)d_out;
    float* out_vd  = out;
    float* out_h1  = out + (long)BB * VE;
    float* out_c1  = out_h1 + BB * DD;
    float* out_ctx = out_c1 + BB * DD;
    float* out_att = out_ctx + BB * D2;
    float* out_cov = out_att + BB * TT;

    char* p = (char*)d_ws;
    unsigned short* whtswz = (unsigned short*)p; p += (size_t)D2 * D2 * 2;      // 2 MB
    float* xbuf    = (float*)p;  p += (size_t)BB * EE * 4;
    float* dechat  = (float*)p;  p += (size_t)BB * D2 * 4;
    float* decfeat = (float*)p;  p += (size_t)BB * D2 * 4;
    float* scorep  = (float*)p;  p += (size_t)4 * MM * 4;                        // 512 KB
    float* pgen    = (float*)p;  p += 256;
    float* hiddenT = (float*)p;  p += (size_t)BB * DD * 4;
    float* ctxpart = (float*)p;  p += (size_t)16 * BB * D2 * 4;                  // 2 MB
    float* logits  = (float*)p;  p += (size_t)BB * VV * 4;                       // 6.43 MB
    unsigned short* encswz = (unsigned short*)p; p += (size_t)MM * D2 * 2;       // 67.1 MB

    k_transpose_wh<<<dim3(32, 32), dim3(32, 8), 0, stream>>>(Wh, whtswz);
    k_enc2bf<<<16384, 256, 0, stream>>>(enc, encswz);
    k_x<<<dim3(BB, 4), 512, 0, stream>>>(dec_in, pcv, embt, Wgx, bgx, xbuf);
    k_lstm<<<dim3(BB, 8), 512, 0, stream>>>(xbuf, h0, c0, Wih, Whh, bih, bhh, out_h1, out_c1, dechat);
    k_decfeat<<<dim3(BB, 16), 512, 0, stream>>>(dechat, Ws, bs, decfeat);
    k_scores<<<1024, 512, 0, stream>>>(encswz, whtswz, decfeat, cov, Wc, vv, scorep);
    k_softmax<<<BB, 256, 0, stream>>>(scorep, mask, cov, out_att, out_cov);
    k_context<<<dim3(BB, 16), 256, 0, stream>>>(encswz, out_att, ctxpart);
    k_ctxreduce<<<(BB * D2) / 256, 256, 0, stream>>>(ctxpart, out_ctx);
    k_pgen<<<BB, 256, 0, stream>>>(out_ctx, dechat, xbuf, Wpg, bpg, pgen);
    k_hidden<<<dim3(BB, 8), 512, 0, stream>>>(out_h1, out_ctx, Wv1, bv1, hiddenT);
    k_logits<<<786, 256, 0, stream>>>(hiddenT, Wv2, bv2, logits);
    k_vocab_all<<<BB, 1024, 0, stream>>>(logits, pgen, extraz, out_att, eiv, out_vd);
}

// Round 7
// 368.855 us; speedup vs baseline: 1.0008x; 1.0008x over previous
//
#include <hip/hip_runtime.h>
#include <hip/hip_bf16.h>

typedef __attribute__((ext_vector_type(4))) float f32x4;
typedef __attribute__((ext_vector_type(8))) short s16x8;
typedef __attribute__((ext_vector_type(4))) short s16x4;

#define DEVINL __device__ __forceinline__

static constexpr int BB = 32, TT = 1024, DD = 512, EE = 256, VV = 50257, EXTRA = 200;
static constexpr int D2 = 1024;           // 2*D
static constexpr int VE = VV + EXTRA;     // 50457
static constexpr long MM = (long)BB * TT; // 32768

DEVINL unsigned short f2bf(float x) {
    union { float f; unsigned int u; } c; c.f = x;
    unsigned int u = c.u;
    u += 0x7fffu + ((u >> 16) & 1u);   // round-to-nearest-even
    return (unsigned short)(u >> 16);
}
DEVINL float bf2f(unsigned short h) {
    union { unsigned int u; float f; } c; c.u = ((unsigned int)h) << 16;
    return c.f;
}
DEVINL float sigmoidf_(float x) { return 1.0f / (1.0f + __expf(-x)); }
DEVINL float tanh_fast(float x) {
    x = fminf(15.f, fmaxf(-15.f, x));
    float e = __expf(2.f * x);
    return (e - 1.f) / (e + 1.f);
}
DEVINL void gl16(const void* g, void* l) {  // 16B global->LDS direct (dest: wave base + lane*16)
    __builtin_amdgcn_global_load_lds((__attribute__((address_space(1))) void*)g,
                                     (__attribute__((address_space(3))) void*)l, 16, 0, 0);
}

// ---------------------------------------------------------------- K0: W_h^T -> bf16, k-swizzled
// whtswz[n][k] = bf16(Wh[k ^ ((n&7)<<3)][n])
__global__ void k_transpose_wh(const float* __restrict__ Wh, unsigned short* __restrict__ WhT) {
    __shared__ float tile[32][33];
    int n0 = blockIdx.x * 32, k0 = blockIdx.y * 32;
    int tx = threadIdx.x, ty = threadIdx.y;  // 32 x 8
    #pragma unroll
    for (int i = 0; i < 4; i++)
        tile[ty + i * 8][tx] = Wh[(long)(k0 + ty + i * 8) * D2 + n0 + tx];
    __syncthreads();
    #pragma unroll
    for (int i = 0; i < 4; i++) {
        int n = n0 + ty + i * 8;
        int kcol = (k0 + tx) ^ ((n & 7) << 3);
        WhT[(long)n * D2 + kcol] = f2bf(tile[tx][ty + i * 8]);
    }
}

// ---------------------------------------------------------------- K0b: enc f32 -> bf16, k-swizzled
// encswz[m][k] = bf16(enc[m][k ^ ((m&7)<<3)])
__global__ void k_enc2bf(const float* __restrict__ enc, unsigned short* __restrict__ dst) {
    long idx = (long)blockIdx.x * 256 + threadIdx.x;  // 16384 blocks
    int m  = (int)(idx >> 7);
    int k2 = (int)(idx & 127) * 8;
    int s  = (m & 7) << 3;
    const float* src = enc + (long)m * 1024 + (k2 ^ s);
    f32x4 a = *(const f32x4*)src;
    f32x4 b = *(const f32x4*)(src + 4);
    s16x8 h;
    h[0] = (short)f2bf(a[0]); h[1] = (short)f2bf(a[1]); h[2] = (short)f2bf(a[2]); h[3] = (short)f2bf(a[3]);
    h[4] = (short)f2bf(b[0]); h[5] = (short)f2bf(b[1]); h[6] = (short)f2bf(b[2]); h[7] = (short)f2bf(b[3]);
    *(s16x8*)(dst + (long)m * 1024 + k2) = h;
}

// ---------------------------------------------------------------- K1: x = [pcv|emb] @ W_gx + b_gx
__global__ __launch_bounds__(512) void k_x(
    const int* __restrict__ dec_in, const float* __restrict__ pcv,
    const float* __restrict__ embt, const float* __restrict__ Wgx,
    const float* __restrict__ bgx, float* __restrict__ xbuf) {
    __shared__ float xs[1280];
    __shared__ float sred[8][64];
    int b = blockIdx.x, n0 = blockIdx.y * 64;     // grid (32,4)
    int tid = threadIdx.x, nl = tid & 63, ks = tid >> 6;   // 8 k-slices x 160
    long er = (long)dec_in[b] * EE;
    for (int i = tid; i < 1280; i += 512)
        xs[i] = (i < 1024) ? pcv[b * 1024 + i] : embt[er + i - 1024];
    __syncthreads();
    float acc = 0.f;
    for (int k = ks * 160; k < ks * 160 + 160; ++k)
        acc += xs[k] * Wgx[(long)k * EE + n0 + nl];
    sred[ks][nl] = acc;
    __syncthreads();
    if (tid < 64) {
        int n = n0 + tid;
        float s = bgx[n];
        #pragma unroll
        for (int i = 0; i < 8; i++) s += sred[i][tid];
        xbuf[b * EE + n] = s;
    }
}

// ---------------------------------------------------------------- K2: LSTM cell (fused k-split)
__global__ __launch_bounds__(512) void k_lstm(
    const float* __restrict__ xbuf, const float* __restrict__ h0,
    const float* __restrict__ c0, const float* __restrict__ Wih,
    const float* __restrict__ Whh, const float* __restrict__ bih,
    const float* __restrict__ bhh, float* __restrict__ h1o,
    float* __restrict__ c1o, float* __restrict__ dechat) {
    __shared__ float xs[768];
    __shared__ float sred[4][8][64];
    int b = blockIdx.x, d0 = blockIdx.y * 64;     // grid (32,8)
    int tid = threadIdx.x, dl = tid & 63, ks = tid >> 6;   // 8 k-slices x 96
    for (int i = tid; i < 768; i += 512)
        xs[i] = (i < 256) ? xbuf[b * 256 + i] : h0[b * 512 + i - 256];
    __syncthreads();
    float a0 = 0, a1 = 0, a2 = 0, a3 = 0;
    for (int k = ks * 96; k < ks * 96 + 96; ++k) {
        float xv = xs[k];
        const float* wr = (k < 256) ? (Wih + (long)k * 2048) : (Whh + (long)(k - 256) * 2048);
        a0 += xv * wr[d0 + dl];        a1 += xv * wr[512 + d0 + dl];
        a2 += xv * wr[1024 + d0 + dl]; a3 += xv * wr[1536 + d0 + dl];
    }
    sred[0][ks][dl] = a0; sred[1][ks][dl] = a1; sred[2][ks][dl] = a2; sred[3][ks][dl] = a3;
    __syncthreads();
    if (tid < 64) {
        int d = d0 + tid;
        float gi = bih[d] + bhh[d];
        float gf = bih[512 + d] + bhh[512 + d];
        float gg = bih[1024 + d] + bhh[1024 + d];
        float go = bih[1536 + d] + bhh[1536 + d];
        #pragma unroll
        for (int s = 0; s < 8; s++) {
            gi += sred[0][s][tid]; gf += sred[1][s][tid];
            gg += sred[2][s][tid]; go += sred[3][s][tid];
        }
        float c1 = sigmoidf_(gf) * c0[b * 512 + d] + sigmoidf_(gi) * tanh_fast(gg);
        float h1 = sigmoidf_(go) * tanh_fast(c1);
        h1o[b * 512 + d] = h1; c1o[b * 512 + d] = c1;
        dechat[b * 1024 + d] = h1; dechat[b * 1024 + 512 + d] = c1;
    }
}

// ---------------------------------------------------------------- K3: dec_feat = dec_hat @ W_s + b_s
__global__ __launch_bounds__(512) void k_decfeat(
    const float* __restrict__ dechat, const float* __restrict__ Ws,
    const float* __restrict__ bs, float* __restrict__ decfeat) {
    __shared__ float xs[1024];
    __shared__ float sred[8][64];
    int b = blockIdx.x, n0 = blockIdx.y * 64;     // grid (32,16)
    int tid = threadIdx.x, nl = tid & 63, ks = tid >> 6;   // 8 x 128
    for (int i = tid; i < 1024; i += 512) xs[i] = dechat[b * 1024 + i];
    __syncthreads();
    float acc = 0.f;
    for (int k = ks * 128; k < ks * 128 + 128; ++k)
        acc += xs[k] * Ws[(long)k * 1024 + n0 + nl];
    sred[ks][nl] = acc;
    __syncthreads();
    if (tid < 64) {
        int n = n0 + tid;
        float s = bs[n];
        #pragma unroll
        for (int i = 0; i < 8; i++) s += sred[i][tid];
        decfeat[b * 1024 + n] = s;
    }
}

// ---------------------------------------------------------------- K4: fused attention scores (R2 structure)
__global__ __launch_bounds__(512) void k_scores(
    const unsigned short* __restrict__ encswz, const unsigned short* __restrict__ whtswz,
    const float* __restrict__ decfeat, const float* __restrict__ cov,
    const float* __restrict__ Wc, const float* __restrict__ vvec,
    float* __restrict__ scorep) {
    __shared__ __align__(16) unsigned short As[128 * 64];   // 16 KB, linear, data pre-swizzled
    __shared__ __align__(16) unsigned short Bs[256 * 64];   // 32 KB
    __shared__ float sred[4][128];                          // total 50 KB -> 3 blocks/CU
    const int tid = threadIdx.x;
    const int lane = tid & 63, wave = tid >> 6;
    const int wid = __builtin_amdgcn_readfirstlane(wave);
    const int g = lane >> 4, c = lane & 15;
    const int wm = wave >> 2, wn = wave & 3;   // 2 x 4 waves over 128m x 256n

    const int bid = blockIdx.x;
    const int xcd = bid & 7, t = bid >> 3;
    const int mt = xcd * 32 + (t >> 2), nt = t & 3;
    const long m0 = (long)mt * 128;
    const int n0 = nt * 256;
    const int bblk = mt >> 3;                  // batch row

    const int arow = wid * 16 + (lane >> 3);
    const int axo  = (lane & 7) * 8;
    const int brow = wid * 32 + (lane >> 3);
    unsigned short* aBase = &As[wid * 1024];
    unsigned short* bBase = &Bs[wid * 2048];

    f32x4 acc[4][4];
    #pragma unroll
    for (int i = 0; i < 4; i++)
        #pragma unroll
        for (int j = 0; j < 4; j++) acc[i][j] = (f32x4){0.f, 0.f, 0.f, 0.f};

    const int sx = (c & 7) << 3;               // read-side swizzle

    for (int kt = 0; kt < 16; ++kt) {
        const int k0 = kt * 64;
        __syncthreads();
        gl16(encswz + (m0 + arow) * 1024 + k0 + axo,       aBase);
        gl16(encswz + (m0 + arow + 8) * 1024 + k0 + axo,   aBase + 512);
        gl16(whtswz + (long)(n0 + brow) * 1024 + k0 + axo,        bBase);
        gl16(whtswz + (long)(n0 + brow + 8) * 1024 + k0 + axo,    bBase + 512);
        gl16(whtswz + (long)(n0 + brow + 16) * 1024 + k0 + axo,   bBase + 1024);
        gl16(whtswz + (long)(n0 + brow + 24) * 1024 + k0 + axo,   bBase + 1536);
        __syncthreads();                       // drains vmcnt(0)
        #pragma unroll
        for (int kk = 0; kk < 2; ++kk) {
            const int kse = (kk * 32 + g * 8) ^ sx;
            s16x8 af[4], bfj[4];
            #pragma unroll
            for (int i = 0; i < 4; i++) af[i] = *(const s16x8*)&As[(wm * 64 + i * 16 + c) * 64 + kse];
            #pragma unroll
            for (int j = 0; j < 4; j++) bfj[j] = *(const s16x8*)&Bs[(wn * 64 + j * 16 + c) * 64 + kse];
            #pragma unroll
            for (int i = 0; i < 4; i++)
                #pragma unroll
                for (int j = 0; j < 4; j++)
                    acc[i][j] = __builtin_amdgcn_mfma_f32_16x16x32_bf16(af[i], bfj[j], acc[i][j], 0, 0, 0);
        }
    }
    float dfv[4], wcv[4], vvj[4];
    #pragma unroll
    for (int j = 0; j < 4; j++) {
        int col = n0 + wn * 64 + j * 16 + c;
        dfv[j] = decfeat[bblk * D2 + col];
        wcv[j] = Wc[col];
        vvj[j] = vvec[col];
    }
    float sAcc[4][4];
    #pragma unroll
    for (int i = 0; i < 4; i++) {
        #pragma unroll
        for (int r = 0; r < 4; r++) {
            const long m = m0 + wm * 64 + i * 16 + g * 4 + r;
            const float covm = cov[m];
            float su = 0.f;
            #pragma unroll
            for (int j = 0; j < 4; j++) {
                float e = acc[i][j][r] + dfv[j] + covm * wcv[j];
                su += tanh_fast(e) * vvj[j];
            }
            su += __shfl_xor(su, 1); su += __shfl_xor(su, 2);
            su += __shfl_xor(su, 4); su += __shfl_xor(su, 8);
            sAcc[i][r] = su;
        }
    }
    if (c == 0) {
        #pragma unroll
        for (int i = 0; i < 4; i++)
            #pragma unroll
            for (int r = 0; r < 4; r++)
                sred[wn][wm * 64 + i * 16 + g * 4 + r] = sAcc[i][r];
    }
    __syncthreads();
    if (tid < 128)
        scorep[(long)nt * MM + m0 + tid] = sred[0][tid] + sred[1][tid] + sred[2][tid] + sred[3][tid];
}

// ---------------------------------------------------------------- K5: softmax + mask renorm
__global__ void k_softmax(const float* __restrict__ scorep, const float* __restrict__ mask,
                          const float* __restrict__ cov, float* __restrict__ att,
                          float* __restrict__ covn) {
    int b = blockIdx.x, tid = threadIdx.x;  // 256 threads
    __shared__ float sm[8];
    float sv[4];
    float mx = -1e30f;
    #pragma unroll
    for (int i = 0; i < 4; i++) {
        long idx = (long)b * TT + tid + 256 * i;
        sv[i] = scorep[idx] + scorep[MM + idx] + scorep[2 * MM + idx] + scorep[3 * MM + idx];
        mx = fmaxf(mx, sv[i]);
    }
    for (int o = 32; o; o >>= 1) mx = fmaxf(mx, __shfl_xor(mx, o));
    if ((tid & 63) == 0) sm[tid >> 6] = mx;
    __syncthreads();
    mx = fmaxf(fmaxf(sm[0], sm[1]), fmaxf(sm[2], sm[3]));
    __syncthreads();
    float e[4]; float s = 0.f;
    #pragma unroll
    for (int i = 0; i < 4; i++) { e[i] = __expf(sv[i] - mx); s += e[i]; }
    for (int o = 32; o; o >>= 1) s += __shfl_xor(s, o);
    if ((tid & 63) == 0) sm[tid >> 6] = s;
    __syncthreads();
    s = sm[0] + sm[1] + sm[2] + sm[3];
    __syncthreads();
    float inv = 1.f / s;
    float am[4]; float s2 = 0.f;
    #pragma unroll
    for (int i = 0; i < 4; i++) { am[i] = e[i] * inv * mask[b * TT + tid + 256 * i]; s2 += am[i]; }
    for (int o = 32; o; o >>= 1) s2 += __shfl_xor(s2, o);
    if ((tid & 63) == 0) sm[tid >> 6] = s2;
    __syncthreads();
    s2 = sm[0] + sm[1] + sm[2] + sm[3];
    float inv2 = 1.f / s2;
    #pragma unroll
    for (int i = 0; i < 4; i++) {
        int t = tid + 256 * i;
        float a = am[i] * inv2;
        att[b * TT + t] = a;
        covn[b * TT + t] = cov[b * TT + t] + a;
    }
}

// ---------------------------------------------------------------- K6: context partials (bf16 enc) + reduce
__global__ void k_context(const unsigned short* __restrict__ encswz, const float* __restrict__ att,
                          float* __restrict__ part) {
    int b = blockIdx.x, tc = blockIdx.y;  // grid (32,16)
    int d4 = threadIdx.x;                 // 256 threads -> d = d4*4
    float a0 = 0, a1 = 0, a2 = 0, a3 = 0;
    const float* ab = att + b * TT;
    for (int t = tc * 64; t < tc * 64 + 64; ++t) {
        float a = ab[t];
        int sx = (t & 7) << 3;
        const unsigned short* ep = encswz + ((long)b * TT + t) * D2 + ((d4 * 4) ^ sx);
        s16x4 ev = *(const s16x4*)ep;
        a0 += a * bf2f((unsigned short)ev[0]); a1 += a * bf2f((unsigned short)ev[1]);
        a2 += a * bf2f((unsigned short)ev[2]); a3 += a * bf2f((unsigned short)ev[3]);
    }
    float* pp = part + (long)tc * BB * D2 + b * D2 + d4 * 4;
    pp[0] = a0; pp[1] = a1; pp[2] = a2; pp[3] = a3;
}

__global__ void k_ctxreduce(const float* __restrict__ part, float* __restrict__ ctx) {
    int i = blockIdx.x * 256 + threadIdx.x;  // 128 blocks
    float s = 0.f;
    #pragma unroll
    for (int p = 0; p < 16; p++) s += part[(long)p * BB * D2 + i];
    ctx[i] = s;
}

// ---------------------------------------------------------------- K7a: p_gen
__global__ void k_pgen(const float* __restrict__ ctx, const float* __restrict__ dechat,
                       const float* __restrict__ xbuf, const float* __restrict__ Wpg,
                       const float* __restrict__ bpg, float* __restrict__ pgen) {
    int b = blockIdx.x, tid = threadIdx.x;  // 256 threads
    __shared__ float sm[8];
    float acc = 0.f;
    for (int k = tid; k < D2; k += 256)
        acc += ctx[b * D2 + k] * Wpg[k] + dechat[b * D2 + k] * Wpg[D2 + k];
    acc += xbuf[b * EE + tid] * Wpg[2 * D2 + tid];
    for (int o = 32; o; o >>= 1) acc += __shfl_xor(acc, o);
    if ((tid & 63) == 0) sm[tid >> 6] = acc;
    __syncthreads();
    if (tid == 0) {
        float t = sm[0] + sm[1] + sm[2] + sm[3];
        pgen[b] = sigmoidf_(t + bpg[0]);
    }
}

// ---------------------------------------------------------------- K7b: hiddenT = ([h1|ctx] @ W_v1 + b_v1)^T
__global__ __launch_bounds__(512) void k_hidden(
    const float* __restrict__ h1, const float* __restrict__ ctx,
    const float* __restrict__ Wv1, const float* __restrict__ bv1,
    float* __restrict__ hiddenT) {
    __shared__ float xs[1536];
    __shared__ float sred[8][64];
    int b = blockIdx.x, n0 = blockIdx.y * 64;   // grid (32,8)
    int tid = threadIdx.x, nl = tid & 63, ks = tid >> 6;   // 8 x 192
    for (int i = tid; i < 1536; i += 512)
        xs[i] = (i < 512) ? h1[b * 512 + i] : ctx[b * 1024 + i - 512];
    __syncthreads();
    float acc = 0.f;
    for (int k = ks * 192; k < ks * 192 + 192; ++k)
        acc += xs[k] * Wv1[(long)k * 512 + n0 + nl];
    sred[ks][nl] = acc;
    __syncthreads();
    if (tid < 64) {
        int n = n0 + tid;
        float s = bv1[n];
        #pragma unroll
        for (int i = 0; i < 8; i++) s += sred[i][tid];
        hiddenT[n * 32 + b] = s;       // [k][b] layout for k_logits s_load path
    }
}

// ---------------------------------------------------------------- K8: logits = hidden @ W_v2 + b_v2
// 256 thr = 4 waves; wave w covers k in [w*128, w*128+128) for the block's 64 v-cols.
// acc[32] in VGPRs, hiddenT via block-uniform s_load, LDS cross-wave reduce.
__global__ __launch_bounds__(256) void k_logits(const float* __restrict__ hiddenT,
                                                const float* __restrict__ Wv2,
                                                const float* __restrict__ bv2,
                                                float* __restrict__ logits) {
    __shared__ float red[4][32][64];   // 32 KB
    int tid = threadIdx.x;
    int lane = tid & 63, w = tid >> 6;
    int v = blockIdx.x * 64 + lane;
    int vs = (v < VV) ? v : (VV - 1);  // safe address for loads
    float acc[32];
    #pragma unroll
    for (int i = 0; i < 32; i++) acc[i] = 0.f;
    const float* wp = Wv2 + vs;
    const int k0 = w * 128;
    #pragma unroll 8
    for (int kk = 0; kk < 128; ++kk) {
        int k = k0 + kk;
        float wv = wp[(long)k * VV];
        const float* h = hiddenT + k * 32;   // block-uniform -> s_load
        #pragma unroll
        for (int b = 0; b < 32; b++) acc[b] += h[b] * wv;
    }
    #pragma unroll
    for (int b = 0; b < 32; b++) red[w][b][lane] = acc[b];
    __syncthreads();
    // 256 threads: each writes 8 (b, v) outputs; lanes -> consecutive v (coalesced)
    int vl = tid & 63, bg = (tid >> 6) * 8;
    int vo = blockIdx.x * 64 + vl;
    if (vo < VV) {
        float bvv = bv2[vo];
        #pragma unroll
        for (int i = 0; i < 8; i++) {
            int b = bg + i;
            float s = red[0][b][vl] + red[1][b][vl] + red[2][b][vl] + red[3][b][vl] + bvv;
            logits[(long)b * VV + vo] = s;
        }
    }
}

// ---------------------------------------------------------------- K9: fused rowstats + vocab_final + scatter
__global__ __launch_bounds__(1024) void k_vocab_all(
    const float* __restrict__ logits, const float* __restrict__ pgen,
    const float* __restrict__ extraz, const float* __restrict__ att,
    const int* __restrict__ eiv, float* __restrict__ out0) {
    int b = blockIdx.x, tid = threadIdx.x;   // 32 blocks x 1024 thr
    __shared__ float sm[16];
    const float* lr = logits + (long)b * VV;
    float mx = -1e30f;
    for (int v = tid; v < VV; v += 1024) mx = fmaxf(mx, lr[v]);
    for (int o = 32; o; o >>= 1) mx = fmaxf(mx, __shfl_xor(mx, o));
    if ((tid & 63) == 0) sm[tid >> 6] = mx;
    __syncthreads();
    #pragma unroll
    for (int i = 0; i < 16; i++) mx = fmaxf(mx, sm[i]);
    __syncthreads();
    float s = 0.f;
    for (int v = tid; v < VV; v += 1024) s += __expf(lr[v] - mx);
    for (int o = 32; o; o >>= 1) s += __shfl_xor(s, o);
    if ((tid & 63) == 0) sm[tid >> 6] = s;
    __syncthreads();
    s = 0.f;
    #pragma unroll
    for (int i = 0; i < 16; i++) s += sm[i];
    float pg = pgen[b];
    float inv = pg / s;
    float* orow = out0 + (long)b * VE;
    for (int v = tid; v < VV; v += 1024) orow[v] = __expf(lr[v] - mx) * inv;
    if (tid < EXTRA) orow[VV + tid] = extraz[b * EXTRA + tid];
    __syncthreads();
    float a = (1.f - pg) * att[b * TT + tid];
    atomicAdd(orow + eiv[b * TT + tid], a);
}

// ================================================================ host
extern "C" void kernel_launch(void* const* d_in, const int* in_sizes, int n_in,
                              void* d_out, int out_size, void* d_ws, size_t ws_size,
                              hipStream_t stream) {
    const int*   dec_in = (const int*)d_in[0];
    const float* h0     = (const float*)d_in[1];
    const float* c0     = (const float*)d_in[2];
    const float* enc    = (const float*)d_in[3];
    const float* mask   = (const float*)d_in[4];
    const float* pcv    = (const float*)d_in[5];
    const float* cov    = (const float*)d_in[6];
    const float* extraz = (const float*)d_in[7];
    const int*   eiv    = (const int*)d_in[8];
    /* d_in[9] = step (unused, training path) */
    const float* embt   = (const float*)d_in[10];
    const float* Wgx    = (const float*)d_in[11];
    const float* bgx    = (const float*)d_in[12];
    const float* Wih    = (const float*)d_in[13];
    const float* Whh    = (const float*)d_in[14];
    const float* bih    = (const float*)d_in[15];
    const float* bhh    = (const float*)d_in[16];
    const float* Wh     = (const float*)d_in[17];
    const float* Wc     = (const float*)d_in[18];
    const float* Ws     = (const float*)d_in[19];
    const float* bs     = (const float*)d_in[20];
    const float* vv     = (const float*)d_in[21];
    const float* Wpg    = (const float*)d_in[22];
    const float* bpg    = (const float*)d_in[23];
    const float* Wv1    = (const float*)d_in[24];
    const float* bv1    = (const float*)d_in[25];
    const float* Wv2    = (const float*)d_in[26];
    const float* bv2    = (const float*)d_in[27];

    float* out = (float*)d_out;
    float* out_vd  = out;
    float* out_h1  = out + (long)BB * VE;
    float* out_c1  = out_h1 + BB * DD;
    float* out_ctx = out_c1 + BB * DD;
    float* out_att = out_ctx + BB * D2;
    float* out_cov = out_att + BB * TT;

    char* p = (char*)d_ws;
    unsigned short* whtswz = (unsigned short*)p; p += (size_t)D2 * D2 * 2;      // 2 MB
    float* xbuf    = (float*)p;  p += (size_t)BB * EE * 4;
    float* dechat  = (float*)p;  p += (size_t)BB * D2 * 4;
    float* decfeat = (float*)p;  p += (size_t)BB * D2 * 4;
    float* scorep  = (float*)p;  p += (size_t)4 * MM * 4;                        // 512 KB
    float* pgen    = (float*)p;  p += 256;
    float* hiddenT = (float*)p;  p += (size_t)BB * DD * 4;
    float* ctxpart = (float*)p;  p += (size_t)16 * BB * D2 * 4;                  // 2 MB
    float* logits  = (float*)p;  p += (size_t)BB * VV * 4;                       // 6.43 MB
    unsigned short* encswz = (unsigned short*)p; p += (size_t)MM * D2 * 2;       // 67.1 MB

    k_transpose_wh<<<dim3(32, 32), dim3(32, 8), 0, stream>>>(Wh, whtswz);
    k_enc2bf<<<16384, 256, 0, stream>>>(enc, encswz);
    k_x<<<dim3(BB, 4), 512, 0, stream>>>(dec_in, pcv, embt, Wgx, bgx, xbuf);
    k_lstm<<<dim3(BB, 8), 512, 0, stream>>>(xbuf, h0, c0, Wih, Whh, bih, bhh, out_h1, out_c1, dechat);
    k_decfeat<<<dim3(BB, 16), 512, 0, stream>>>(dechat, Ws, bs, decfeat);
    k_scores<<<1024, 512, 0, stream>>>(encswz, whtswz, decfeat, cov, Wc, vv, scorep);
    k_softmax<<<BB, 256, 0, stream>>>(scorep, mask, cov, out_att, out_cov);
    k_context<<<dim3(BB, 16), 256, 0, stream>>>(encswz, out_att, ctxpart);
    k_ctxreduce<<<(BB * D2) / 256, 256, 0, stream>>>(ctxpart, out_ctx);
    k_pgen<<<BB, 256, 0, stream>>>(out_ctx, dechat, xbuf, Wpg, bpg, pgen);
    k_hidden<<<dim3(BB, 8), 512, 0, stream>>>(out_h1, out_ctx, Wv1, bv1, hiddenT);
    k_logits<<<786, 256, 0, stream>>>(hiddenT, Wv2, bv2, logits);
    k_vocab_all<<<BB, 1024, 0, stream>>>(logits, pgen, extraz, out_att, eiv, out_vd);
}

// Round 8
// 277.891 us; speedup vs baseline: 1.3284x; 1.3273x over previous
//
#include <hip/hip_runtime.h>
#include <hip/hip_bf16.h>

typedef __attribute__((ext_vector_type(4))) float f32x4;
typedef __attribute__((ext_vector_type(8))) short s16x8;
typedef __attribute__((ext_vector_type(4))) short s16x4;

#define DEVINL __device__ __forceinline__

static constexpr int BB = 32, TT = 1024, DD = 512, EE = 256, VV = 50257, EXTRA = 200;
static constexpr int D2 = 1024;           // 2*D
static constexpr int VE = VV + EXTRA;     // 50457
static constexpr long MM = (long)BB * TT; // 32768
static constexpr int VPAD = 50304;        // 786*64, padded v rows for wv2t

DEVINL unsigned short f2bf(float x) {
    union { float f; unsigned int u; } c; c.f = x;
    unsigned int u = c.u;
    u += 0x7fffu + ((u >> 16) & 1u);   // round-to-nearest-even
    return (unsigned short)(u >> 16);
}
DEVINL float bf2f(unsigned short h) {
    union { unsigned int u; float f; } c; c.u = ((unsigned int)h) << 16;
    return c.f;
}
DEVINL float sigmoidf_(float x) { return 1.0f / (1.0f + __expf(-x)); }
DEVINL float tanh_fast(float x) {
    x = fminf(15.f, fmaxf(-15.f, x));
    float e = __expf(2.f * x);
    return (e - 1.f) / (e + 1.f);
}
DEVINL void gl16(const void* g, void* l) {  // 16B global->LDS direct (dest: wave base + lane*16)
    __builtin_amdgcn_global_load_lds((__attribute__((address_space(1))) void*)g,
                                     (__attribute__((address_space(3))) void*)l, 16, 0, 0);
}

// ---------------------------------------------------------------- K0: W_h^T -> bf16, k-swizzled
// whtswz[n][k] = bf16(Wh[k ^ ((n&7)<<3)][n])
__global__ void k_transpose_wh(const float* __restrict__ Wh, unsigned short* __restrict__ WhT) {
    __shared__ float tile[32][33];
    int n0 = blockIdx.x * 32, k0 = blockIdx.y * 32;
    int tx = threadIdx.x, ty = threadIdx.y;  // 32 x 8
    #pragma unroll
    for (int i = 0; i < 4; i++)
        tile[ty + i * 8][tx] = Wh[(long)(k0 + ty + i * 8) * D2 + n0 + tx];
    __syncthreads();
    #pragma unroll
    for (int i = 0; i < 4; i++) {
        int n = n0 + ty + i * 8;
        int kcol = (k0 + tx) ^ ((n & 7) << 3);
        WhT[(long)n * D2 + kcol] = f2bf(tile[tx][ty + i * 8]);
    }
}

// ---------------------------------------------------------------- K0b: enc f32 -> bf16, k-swizzled
// encswz[m][k] = bf16(enc[m][k ^ ((m&7)<<3)])
__global__ void k_enc2bf(const float* __restrict__ enc, unsigned short* __restrict__ dst) {
    long idx = (long)blockIdx.x * 256 + threadIdx.x;  // 16384 blocks
    int m  = (int)(idx >> 7);
    int k2 = (int)(idx & 127) * 8;
    int s  = (m & 7) << 3;
    const float* src = enc + (long)m * 1024 + (k2 ^ s);
    f32x4 a = *(const f32x4*)src;
    f32x4 b = *(const f32x4*)(src + 4);
    s16x8 h;
    h[0] = (short)f2bf(a[0]); h[1] = (short)f2bf(a[1]); h[2] = (short)f2bf(a[2]); h[3] = (short)f2bf(a[3]);
    h[4] = (short)f2bf(b[0]); h[5] = (short)f2bf(b[1]); h[6] = (short)f2bf(b[2]); h[7] = (short)f2bf(b[3]);
    *(s16x8*)(dst + (long)m * 1024 + k2) = h;
}

// ---------------------------------------------------------------- K0c: Wv2^T -> bf16, k-swizzled, padded
// wv2t[v][k] = bf16(Wv2[k ^ ((v&7)<<3)][v]); rows v in [VV, VPAD) = 0
__global__ void k_wv2t(const float* __restrict__ Wv2, unsigned short* __restrict__ out) {
    __shared__ float tile[32][33];
    int v0 = blockIdx.x * 32, k0 = blockIdx.y * 32;   // grid (1572, 16)
    int tx = threadIdx.x, ty = threadIdx.y;           // 32 x 8
    #pragma unroll
    for (int i = 0; i < 4; i++) {
        int k = k0 + ty + i * 8;
        int v = v0 + tx;
        tile[ty + i * 8][tx] = (v < VV) ? Wv2[(long)k * VV + v] : 0.f;
    }
    __syncthreads();
    #pragma unroll
    for (int i = 0; i < 4; i++) {
        int v = v0 + ty + i * 8;
        int kcol = (k0 + tx) ^ ((v & 7) << 3);
        out[(long)v * 512 + kcol] = f2bf(tile[tx][ty + i * 8]);
    }
}

// ---------------------------------------------------------------- K1: x = [pcv|emb] @ W_gx + b_gx
__global__ __launch_bounds__(512) void k_x(
    const int* __restrict__ dec_in, const float* __restrict__ pcv,
    const float* __restrict__ embt, const float* __restrict__ Wgx,
    const float* __restrict__ bgx, float* __restrict__ xbuf) {
    __shared__ float xs[1280];
    __shared__ float sred[8][64];
    int b = blockIdx.x, n0 = blockIdx.y * 64;     // grid (32,4)
    int tid = threadIdx.x, nl = tid & 63, ks = tid >> 6;   // 8 k-slices x 160
    long er = (long)dec_in[b] * EE;
    for (int i = tid; i < 1280; i += 512)
        xs[i] = (i < 1024) ? pcv[b * 1024 + i] : embt[er + i - 1024];
    __syncthreads();
    float acc = 0.f;
    for (int k = ks * 160; k < ks * 160 + 160; ++k)
        acc += xs[k] * Wgx[(long)k * EE + n0 + nl];
    sred[ks][nl] = acc;
    __syncthreads();
    if (tid < 64) {
        int n = n0 + tid;
        float s = bgx[n];
        #pragma unroll
        for (int i = 0; i < 8; i++) s += sred[i][tid];
        xbuf[b * EE + n] = s;
    }
}

// ---------------------------------------------------------------- K2: LSTM cell (fused k-split)
__global__ __launch_bounds__(512) void k_lstm(
    const float* __restrict__ xbuf, const float* __restrict__ h0,
    const float* __restrict__ c0, const float* __restrict__ Wih,
    const float* __restrict__ Whh, const float* __restrict__ bih,
    const float* __restrict__ bhh, float* __restrict__ h1o,
    float* __restrict__ c1o, float* __restrict__ dechat) {
    __shared__ float xs[768];
    __shared__ float sred[4][8][64];
    int b = blockIdx.x, d0 = blockIdx.y * 64;     // grid (32,8)
    int tid = threadIdx.x, dl = tid & 63, ks = tid >> 6;   // 8 k-slices x 96
    for (int i = tid; i < 768; i += 512)
        xs[i] = (i < 256) ? xbuf[b * 256 + i] : h0[b * 512 + i - 256];
    __syncthreads();
    float a0 = 0, a1 = 0, a2 = 0, a3 = 0;
    for (int k = ks * 96; k < ks * 96 + 96; ++k) {
        float xv = xs[k];
        const float* wr = (k < 256) ? (Wih + (long)k * 2048) : (Whh + (long)(k - 256) * 2048);
        a0 += xv * wr[d0 + dl];        a1 += xv * wr[512 + d0 + dl];
        a2 += xv * wr[1024 + d0 + dl]; a3 += xv * wr[1536 + d0 + dl];
    }
    sred[0][ks][dl] = a0; sred[1][ks][dl] = a1; sred[2][ks][dl] = a2; sred[3][ks][dl] = a3;
    __syncthreads();
    if (tid < 64) {
        int d = d0 + tid;
        float gi = bih[d] + bhh[d];
        float gf = bih[512 + d] + bhh[512 + d];
        float gg = bih[1024 + d] + bhh[1024 + d];
        float go = bih[1536 + d] + bhh[1536 + d];
        #pragma unroll
        for (int s = 0; s < 8; s++) {
            gi += sred[0][s][tid]; gf += sred[1][s][tid];
            gg += sred[2][s][tid]; go += sred[3][s][tid];
        }
        float c1 = sigmoidf_(gf) * c0[b * 512 + d] + sigmoidf_(gi) * tanh_fast(gg);
        float h1 = sigmoidf_(go) * tanh_fast(c1);
        h1o[b * 512 + d] = h1; c1o[b * 512 + d] = c1;
        dechat[b * 1024 + d] = h1; dechat[b * 1024 + 512 + d] = c1;
    }
}

// ---------------------------------------------------------------- K3: dec_feat = dec_hat @ W_s + b_s
__global__ __launch_bounds__(512) void k_decfeat(
    const float* __restrict__ dechat, const float* __restrict__ Ws,
    const float* __restrict__ bs, float* __restrict__ decfeat) {
    __shared__ float xs[1024];
    __shared__ float sred[8][64];
    int b = blockIdx.x, n0 = blockIdx.y * 64;     // grid (32,16)
    int tid = threadIdx.x, nl = tid & 63, ks = tid >> 6;   // 8 x 128
    for (int i = tid; i < 1024; i += 512) xs[i] = dechat[b * 1024 + i];
    __syncthreads();
    float acc = 0.f;
    for (int k = ks * 128; k < ks * 128 + 128; ++k)
        acc += xs[k] * Ws[(long)k * 1024 + n0 + nl];
    sred[ks][nl] = acc;
    __syncthreads();
    if (tid < 64) {
        int n = n0 + tid;
        float s = bs[n];
        #pragma unroll
        for (int i = 0; i < 8; i++) s += sred[i][tid];
        decfeat[b * 1024 + n] = s;
    }
}

// ---------------------------------------------------------------- K4: fused attention scores (R2 structure)
__global__ __launch_bounds__(512) void k_scores(
    const unsigned short* __restrict__ encswz, const unsigned short* __restrict__ whtswz,
    const float* __restrict__ decfeat, const float* __restrict__ cov,
    const float* __restrict__ Wc, const float* __restrict__ vvec,
    float* __restrict__ scorep) {
    __shared__ __align__(16) unsigned short As[128 * 64];   // 16 KB, linear, data pre-swizzled
    __shared__ __align__(16) unsigned short Bs[256 * 64];   // 32 KB
    __shared__ float sred[4][128];                          // total 50 KB -> 3 blocks/CU
    const int tid = threadIdx.x;
    const int lane = tid & 63, wave = tid >> 6;
    const int wid = __builtin_amdgcn_readfirstlane(wave);
    const int g = lane >> 4, c = lane & 15;
    const int wm = wave >> 2, wn = wave & 3;   // 2 x 4 waves over 128m x 256n

    const int bid = blockIdx.x;
    const int xcd = bid & 7, t = bid >> 3;
    const int mt = xcd * 32 + (t >> 2), nt = t & 3;
    const long m0 = (long)mt * 128;
    const int n0 = nt * 256;
    const int bblk = mt >> 3;                  // batch row

    const int arow = wid * 16 + (lane >> 3);
    const int axo  = (lane & 7) * 8;
    const int brow = wid * 32 + (lane >> 3);
    unsigned short* aBase = &As[wid * 1024];
    unsigned short* bBase = &Bs[wid * 2048];

    f32x4 acc[4][4];
    #pragma unroll
    for (int i = 0; i < 4; i++)
        #pragma unroll
        for (int j = 0; j < 4; j++) acc[i][j] = (f32x4){0.f, 0.f, 0.f, 0.f};

    const int sx = (c & 7) << 3;               // read-side swizzle

    for (int kt = 0; kt < 16; ++kt) {
        const int k0 = kt * 64;
        __syncthreads();
        gl16(encswz + (m0 + arow) * 1024 + k0 + axo,       aBase);
        gl16(encswz + (m0 + arow + 8) * 1024 + k0 + axo,   aBase + 512);
        gl16(whtswz + (long)(n0 + brow) * 1024 + k0 + axo,        bBase);
        gl16(whtswz + (long)(n0 + brow + 8) * 1024 + k0 + axo,    bBase + 512);
        gl16(whtswz + (long)(n0 + brow + 16) * 1024 + k0 + axo,   bBase + 1024);
        gl16(whtswz + (long)(n0 + brow + 24) * 1024 + k0 + axo,   bBase + 1536);
        __syncthreads();                       // drains vmcnt(0)
        #pragma unroll
        for (int kk = 0; kk < 2; ++kk) {
            const int kse = (kk * 32 + g * 8) ^ sx;
            s16x8 af[4], bfj[4];
            #pragma unroll
            for (int i = 0; i < 4; i++) af[i] = *(const s16x8*)&As[(wm * 64 + i * 16 + c) * 64 + kse];
            #pragma unroll
            for (int j = 0; j < 4; j++) bfj[j] = *(const s16x8*)&Bs[(wn * 64 + j * 16 + c) * 64 + kse];
            #pragma unroll
            for (int i = 0; i < 4; i++)
                #pragma unroll
                for (int j = 0; j < 4; j++)
                    acc[i][j] = __builtin_amdgcn_mfma_f32_16x16x32_bf16(af[i], bfj[j], acc[i][j], 0, 0, 0);
        }
    }
    float dfv[4], wcv[4], vvj[4];
    #pragma unroll
    for (int j = 0; j < 4; j++) {
        int col = n0 + wn * 64 + j * 16 + c;
        dfv[j] = decfeat[bblk * D2 + col];
        wcv[j] = Wc[col];
        vvj[j] = vvec[col];
    }
    float sAcc[4][4];
    #pragma unroll
    for (int i = 0; i < 4; i++) {
        #pragma unroll
        for (int r = 0; r < 4; r++) {
            const long m = m0 + wm * 64 + i * 16 + g * 4 + r;
            const float covm = cov[m];
            float su = 0.f;
            #pragma unroll
            for (int j = 0; j < 4; j++) {
                float e = acc[i][j][r] + dfv[j] + covm * wcv[j];
                su += tanh_fast(e) * vvj[j];
            }
            su += __shfl_xor(su, 1); su += __shfl_xor(su, 2);
            su += __shfl_xor(su, 4); su += __shfl_xor(su, 8);
            sAcc[i][r] = su;
        }
    }
    if (c == 0) {
        #pragma unroll
        for (int i = 0; i < 4; i++)
            #pragma unroll
            for (int r = 0; r < 4; r++)
                sred[wn][wm * 64 + i * 16 + g * 4 + r] = sAcc[i][r];
    }
    __syncthreads();
    if (tid < 128)
        scorep[(long)nt * MM + m0 + tid] = sred[0][tid] + sred[1][tid] + sred[2][tid] + sred[3][tid];
}

// ---------------------------------------------------------------- K5: softmax + mask renorm
__global__ void k_softmax(const float* __restrict__ scorep, const float* __restrict__ mask,
                          const float* __restrict__ cov, float* __restrict__ att,
                          float* __restrict__ covn) {
    int b = blockIdx.x, tid = threadIdx.x;  // 256 threads
    __shared__ float sm[8];
    float sv[4];
    float mx = -1e30f;
    #pragma unroll
    for (int i = 0; i < 4; i++) {
        long idx = (long)b * TT + tid + 256 * i;
        sv[i] = scorep[idx] + scorep[MM + idx] + scorep[2 * MM + idx] + scorep[3 * MM + idx];
        mx = fmaxf(mx, sv[i]);
    }
    for (int o = 32; o; o >>= 1) mx = fmaxf(mx, __shfl_xor(mx, o));
    if ((tid & 63) == 0) sm[tid >> 6] = mx;
    __syncthreads();
    mx = fmaxf(fmaxf(sm[0], sm[1]), fmaxf(sm[2], sm[3]));
    __syncthreads();
    float e[4]; float s = 0.f;
    #pragma unroll
    for (int i = 0; i < 4; i++) { e[i] = __expf(sv[i] - mx); s += e[i]; }
    for (int o = 32; o; o >>= 1) s += __shfl_xor(s, o);
    if ((tid & 63) == 0) sm[tid >> 6] = s;
    __syncthreads();
    s = sm[0] + sm[1] + sm[2] + sm[3];
    __syncthreads();
    float inv = 1.f / s;
    float am[4]; float s2 = 0.f;
    #pragma unroll
    for (int i = 0; i < 4; i++) { am[i] = e[i] * inv * mask[b * TT + tid + 256 * i]; s2 += am[i]; }
    for (int o = 32; o; o >>= 1) s2 += __shfl_xor(s2, o);
    if ((tid & 63) == 0) sm[tid >> 6] = s2;
    __syncthreads();
    s2 = sm[0] + sm[1] + sm[2] + sm[3];
    float inv2 = 1.f / s2;
    #pragma unroll
    for (int i = 0; i < 4; i++) {
        int t = tid + 256 * i;
        float a = am[i] * inv2;
        att[b * TT + t] = a;
        covn[b * TT + t] = cov[b * TT + t] + a;
    }
}

// ---------------------------------------------------------------- K6: context partials (bf16 enc) + reduce
__global__ void k_context(const unsigned short* __restrict__ encswz, const float* __restrict__ att,
                          float* __restrict__ part) {
    int b = blockIdx.x, tc = blockIdx.y;  // grid (32,16)
    int d4 = threadIdx.x;                 // 256 threads -> d = d4*4
    float a0 = 0, a1 = 0, a2 = 0, a3 = 0;
    const float* ab = att + b * TT;
    for (int t = tc * 64; t < tc * 64 + 64; ++t) {
        float a = ab[t];
        int sx = (t & 7) << 3;
        const unsigned short* ep = encswz + ((long)b * TT + t) * D2 + ((d4 * 4) ^ sx);
        s16x4 ev = *(const s16x4*)ep;
        a0 += a * bf2f((unsigned short)ev[0]); a1 += a * bf2f((unsigned short)ev[1]);
        a2 += a * bf2f((unsigned short)ev[2]); a3 += a * bf2f((unsigned short)ev[3]);
    }
    float* pp = part + (long)tc * BB * D2 + b * D2 + d4 * 4;
    pp[0] = a0; pp[1] = a1; pp[2] = a2; pp[3] = a3;
}

__global__ void k_ctxreduce(const float* __restrict__ part, float* __restrict__ ctx) {
    int i = blockIdx.x * 256 + threadIdx.x;  // 128 blocks
    float s = 0.f;
    #pragma unroll
    for (int p = 0; p < 16; p++) s += part[(long)p * BB * D2 + i];
    ctx[i] = s;
}

// ---------------------------------------------------------------- K7a: p_gen
__global__ void k_pgen(const float* __restrict__ ctx, const float* __restrict__ dechat,
                       const float* __restrict__ xbuf, const float* __restrict__ Wpg,
                       const float* __restrict__ bpg, float* __restrict__ pgen) {
    int b = blockIdx.x, tid = threadIdx.x;  // 256 threads
    __shared__ float sm[8];
    float acc = 0.f;
    for (int k = tid; k < D2; k += 256)
        acc += ctx[b * D2 + k] * Wpg[k] + dechat[b * D2 + k] * Wpg[D2 + k];
    acc += xbuf[b * EE + tid] * Wpg[2 * D2 + tid];
    for (int o = 32; o; o >>= 1) acc += __shfl_xor(acc, o);
    if ((tid & 63) == 0) sm[tid >> 6] = acc;
    __syncthreads();
    if (tid == 0) {
        float t = sm[0] + sm[1] + sm[2] + sm[3];
        pgen[b] = sigmoidf_(t + bpg[0]);
    }
}

// ---------------------------------------------------------------- K7b: hbf = bf16([h1|ctx] @ W_v1 + b_v1), [b][k]
__global__ __launch_bounds__(512) void k_hidden(
    const float* __restrict__ h1, const float* __restrict__ ctx,
    const float* __restrict__ Wv1, const float* __restrict__ bv1,
    unsigned short* __restrict__ hbf) {
    __shared__ float xs[1536];
    __shared__ float sred[8][64];
    int b = blockIdx.x, n0 = blockIdx.y * 64;   // grid (32,8)
    int tid = threadIdx.x, nl = tid & 63, ks = tid >> 6;   // 8 x 192
    for (int i = tid; i < 1536; i += 512)
        xs[i] = (i < 512) ? h1[b * 512 + i] : ctx[b * 1024 + i - 512];
    __syncthreads();
    float acc = 0.f;
    for (int k = ks * 192; k < ks * 192 + 192; ++k)
        acc += xs[k] * Wv1[(long)k * 512 + n0 + nl];
    sred[ks][nl] = acc;
    __syncthreads();
    if (tid < 64) {
        int n = n0 + tid;
        float s = bv1[n];
        #pragma unroll
        for (int i = 0; i < 8; i++) s += sred[i][tid];
        hbf[b * 512 + n] = f2bf(s);    // A-operand for MFMA logits
    }
}

// ---------------------------------------------------------------- K8: logits = hidden @ W_v2 + b_v2 (MFMA)
// 786 blocks x 256 thr (4 waves). Block -> 64 v-cols; wave (wm=w>>1, wn=w&1) -> 16b x 32v.
// B via gl16 from swizzled wv2t; A per-lane from L1-resident hbf.
__global__ __launch_bounds__(256) void k_logits(const unsigned short* __restrict__ hbf,
                                                const unsigned short* __restrict__ wv2t,
                                                const float* __restrict__ bv2,
                                                float* __restrict__ logits) {
    __shared__ __align__(16) unsigned short Bs[64 * 128];   // 16 KB
    const int tid = threadIdx.x;
    const int lane = tid & 63, wave = tid >> 6;
    const int wid = __builtin_amdgcn_readfirstlane(wave);
    const int g = lane >> 4, c = lane & 15;
    const int wm = wave >> 1, wn = wave & 1;
    const long v0 = (long)blockIdx.x * 64;

    // B staging: wave covers rows wid*16..+15; each gl16 = 4 rows (lane>>4) x 16 chunks (lane&15)
    const int srow = wid * 16 + (lane >> 4);
    const int scol = (lane & 15) * 8;
    unsigned short* bBase = &Bs[wid * 16 * 128];

    f32x4 acc[2];
    acc[0] = (f32x4){0.f, 0.f, 0.f, 0.f};
    acc[1] = (f32x4){0.f, 0.f, 0.f, 0.f};
    const int sx = (c & 7) << 3;

    for (int kt = 0; kt < 4; ++kt) {
        const int k0 = kt * 128;
        __syncthreads();
        #pragma unroll
        for (int i = 0; i < 4; i++)
            gl16(wv2t + (v0 + srow + i * 4) * 512 + k0 + scol, bBase + i * 512);
        __syncthreads();                       // drains vmcnt(0)
        #pragma unroll
        for (int kk = 0; kk < 4; ++kk) {
            const int kse = (kk * 32 + g * 8) ^ sx;
            s16x8 af = *(const s16x8*)&hbf[(wm * 16 + c) * 512 + k0 + (kk * 32 + g * 8)];
            s16x8 bf0 = *(const s16x8*)&Bs[(wn * 32 + c) * 128 + kse];
            s16x8 bf1 = *(const s16x8*)&Bs[(wn * 32 + 16 + c) * 128 + kse];
            acc[0] = __builtin_amdgcn_mfma_f32_16x16x32_bf16(af, bf0, acc[0], 0, 0, 0);
            acc[1] = __builtin_amdgcn_mfma_f32_16x16x32_bf16(af, bf1, acc[1], 0, 0, 0);
        }
    }
    // C layout: col=c (v), row=g*4+r (b)
    #pragma unroll
    for (int j = 0; j < 2; j++) {
        long v = v0 + wn * 32 + j * 16 + c;
        if (v < VV) {
            float bvv = bv2[v];
            #pragma unroll
            for (int r = 0; r < 4; r++) {
                int b = wm * 16 + g * 4 + r;
                logits[(long)b * VV + v] = acc[j][r] + bvv;
            }
        }
    }
}

// ---------------------------------------------------------------- K9: fused rowstats + vocab_final + scatter
__global__ __launch_bounds__(1024) void k_vocab_all(
    const float* __restrict__ logits, const float* __restrict__ pgen,
    const float* __restrict__ extraz, const float* __restrict__ att,
    const int* __restrict__ eiv, float* __restrict__ out0) {
    int b = blockIdx.x, tid = threadIdx.x;   // 32 blocks x 1024 thr
    __shared__ float sm[16];
    const float* lr = logits + (long)b * VV;
    float mx = -1e30f;
    for (int v = tid; v < VV; v += 1024) mx = fmaxf(mx, lr[v]);
    for (int o = 32; o; o >>= 1) mx = fmaxf(mx, __shfl_xor(mx, o));
    if ((tid & 63) == 0) sm[tid >> 6] = mx;
    __syncthreads();
    #pragma unroll
    for (int i = 0; i < 16; i++) mx = fmaxf(mx, sm[i]);
    __syncthreads();
    float s = 0.f;
    for (int v = tid; v < VV; v += 1024) s += __expf(lr[v] - mx);
    for (int o = 32; o; o >>= 1) s += __shfl_xor(s, o);
    if ((tid & 63) == 0) sm[tid >> 6] = s;
    __syncthreads();
    s = 0.f;
    #pragma unroll
    for (int i = 0; i < 16; i++) s += sm[i];
    float pg = pgen[b];
    float inv = pg / s;
    float* orow = out0 + (long)b * VE;
    for (int v = tid; v < VV; v += 1024) orow[v] = __expf(lr[v] - mx) * inv;
    if (tid < EXTRA) orow[VV + tid] = extraz[b * EXTRA + tid];
    __syncthreads();
    float a = (1.f - pg) * att[b * TT + tid];
    atomicAdd(orow + eiv[b * TT + tid], a);
}

// ================================================================ host
extern "C" void kernel_launch(void* const* d_in, const int* in_sizes, int n_in,
                              void* d_out, int out_size, void* d_ws, size_t ws_size,
                              hipStream_t stream) {
    const int*   dec_in = (const int*)d_in[0];
    const float* h0     = (const float*)d_in[1];
    const float* c0     = (const float*)d_in[2];
    const float* enc    = (const float*)d_in[3];
    const float* mask   = (const float*)d_in[4];
    const float* pcv    = (const float*)d_in[5];
    const float* cov    = (const float*)d_in[6];
    const float* extraz = (const float*)d_in[7];
    const int*   eiv    = (const int*)d_in[8];
    /* d_in[9] = step (unused, training path) */
    const float* embt   = (const float*)d_in[10];
    const float* Wgx    = (const float*)d_in[11];
    const float* bgx    = (const float*)d_in[12];
    const float* Wih    = (const float*)d_in[13];
    const float* Whh    = (const float*)d_in[14];
    const float* bih    = (const float*)d_in[15];
    const float* bhh    = (const float*)d_in[16];
    const float* Wh     = (const float*)d_in[17];
    const float* Wc     = (const float*)d_in[18];
    const float* Ws     = (const float*)d_in[19];
    const float* bs     = (const float*)d_in[20];
    const float* vv     = (const float*)d_in[21];
    const float* Wpg    = (const float*)d_in[22];
    const float* bpg    = (const float*)d_in[23];
    const float* Wv1    = (const float*)d_in[24];
    const float* bv1    = (const float*)d_in[25];
    const float* Wv2    = (const float*)d_in[26];
    const float* bv2    = (const float*)d_in[27];

    float* out = (float*)d_out;
    float* out_vd  = out;
    float* out_h1  = out + (long)BB * VE;
    float* out_c1  = out_h1 + BB * DD;
    float* out_ctx = out_c1 + BB * DD;
    float* out_att = out_ctx + BB * D2;
    float* out_cov = out_att + BB * TT;

    char* p = (char*)d_ws;
    unsigned short* whtswz = (unsigned short*)p; p += (size_t)D2 * D2 * 2;      // 2 MB
    float* xbuf    = (float*)p;  p += (size_t)BB * EE * 4;
    float* dechat  = (float*)p;  p += (size_t)BB * D2 * 4;
    float* decfeat = (float*)p;  p += (size_t)BB * D2 * 4;
    float* scorep  = (float*)p;  p += (size_t)4 * MM * 4;                        // 512 KB
    float* pgen    = (float*)p;  p += 256;
    unsigned short* hbf = (unsigned short*)p; p += (size_t)BB * DD * 2 + 256;    // 32 KB
    float* ctxpart = (float*)p;  p += (size_t)16 * BB * D2 * 4;                  // 2 MB
    float* logits  = (float*)p;  p += (size_t)BB * VV * 4;                       // 6.43 MB
    unsigned short* encswz = (unsigned short*)p; p += (size_t)MM * D2 * 2;       // 67.1 MB
    unsigned short* wv2t   = (unsigned short*)p; p += (size_t)VPAD * DD * 2;     // 51.5 MB

    k_transpose_wh<<<dim3(32, 32), dim3(32, 8), 0, stream>>>(Wh, whtswz);
    k_enc2bf<<<16384, 256, 0, stream>>>(enc, encswz);
    k_x<<<dim3(BB, 4), 512, 0, stream>>>(dec_in, pcv, embt, Wgx, bgx, xbuf);
    k_lstm<<<dim3(BB, 8), 512, 0, stream>>>(xbuf, h0, c0, Wih, Whh, bih, bhh, out_h1, out_c1, dechat);
    k_decfeat<<<dim3(BB, 16), 512, 0, stream>>>(dechat, Ws, bs, decfeat);
    k_scores<<<1024, 512, 0, stream>>>(encswz, whtswz, decfeat, cov, Wc, vv, scorep);
    k_softmax<<<BB, 256, 0, stream>>>(scorep, mask, cov, out_att, out_cov);
    k_context<<<dim3(BB, 16), 256, 0, stream>>>(encswz, out_att, ctxpart);
    k_ctxreduce<<<(BB * D2) / 256, 256, 0, stream>>>(ctxpart, out_ctx);
    k_pgen<<<BB, 256, 0, stream>>>(out_ctx, dechat, xbuf, Wpg, bpg, pgen);
    k_hidden<<<dim3(BB, 8), 512, 0, stream>>>(out_h1, out_ctx, Wv1, bv1, hbf);
    k_wv2t<<<dim3(VPAD / 32, 16), dim3(32, 8), 0, stream>>>(Wv2, wv2t);
    k_logits<<<VPAD / 64, 256, 0, stream>>>(hbf, wv2t, bv2, logits);
    k_vocab_all<<<BB, 1024, 0, stream>>>(logits, pgen, extraz, out_att, eiv, out_vd);
}

// Round 9
// 253.227 us; speedup vs baseline: 1.4578x; 1.0974x over previous
//
#include <hip/hip_runtime.h>
#include <hip/hip_bf16.h>

typedef __attribute__((ext_vector_type(4))) float f32x4;
typedef __attribute__((ext_vector_type(8))) short s16x8;
typedef __attribute__((ext_vector_type(4))) short s16x4;

#define DEVINL __device__ __forceinline__

static constexpr int BB = 32, TT = 1024, DD = 512, EE = 256, VV = 50257, EXTRA = 200;
static constexpr int D2 = 1024;           // 2*D
static constexpr int VE = VV + EXTRA;     // 50457
static constexpr long MM = (long)BB * TT; // 32768
static constexpr int VPAD = 50304;        // 786*64

DEVINL unsigned short f2bf(float x) {
    union { float f; unsigned int u; } c; c.f = x;
    unsigned int u = c.u;
    u += 0x7fffu + ((u >> 16) & 1u);   // round-to-nearest-even
    return (unsigned short)(u >> 16);
}
DEVINL float bf2f(unsigned short h) {
    union { unsigned int u; float f; } c; c.u = ((unsigned int)h) << 16;
    return c.f;
}
DEVINL float sigmoidf_(float x) { return 1.0f / (1.0f + __expf(-x)); }
DEVINL float tanh_fast(float x) {
    x = fminf(15.f, fmaxf(-15.f, x));
    float e = __expf(2.f * x);
    return (e - 1.f) / (e + 1.f);
}
DEVINL void gl16(const void* g, void* l) {  // 16B global->LDS direct (dest: wave base + lane*16)
    __builtin_amdgcn_global_load_lds((__attribute__((address_space(1))) void*)g,
                                     (__attribute__((address_space(3))) void*)l, 16, 0, 0);
}

// ---------------------------------------------------------------- K0: W_h^T -> bf16, k-swizzled
// whtswz[n][k] = bf16(Wh[k ^ ((n&7)<<3)][n])
__global__ void k_transpose_wh(const float* __restrict__ Wh, unsigned short* __restrict__ WhT) {
    __shared__ float tile[32][33];
    int n0 = blockIdx.x * 32, k0 = blockIdx.y * 32;
    int tx = threadIdx.x, ty = threadIdx.y;  // 32 x 8
    #pragma unroll
    for (int i = 0; i < 4; i++)
        tile[ty + i * 8][tx] = Wh[(long)(k0 + ty + i * 8) * D2 + n0 + tx];
    __syncthreads();
    #pragma unroll
    for (int i = 0; i < 4; i++) {
        int n = n0 + ty + i * 8;
        int kcol = (k0 + tx) ^ ((n & 7) << 3);
        WhT[(long)n * D2 + kcol] = f2bf(tile[tx][ty + i * 8]);
    }
}

// ---------------------------------------------------------------- K0b: enc f32 -> bf16, k-swizzled
// encswz[m][k] = bf16(enc[m][k ^ ((m&7)<<3)])
__global__ void k_enc2bf(const float* __restrict__ enc, unsigned short* __restrict__ dst) {
    long idx = (long)blockIdx.x * 256 + threadIdx.x;  // 16384 blocks
    int m  = (int)(idx >> 7);
    int k2 = (int)(idx & 127) * 8;
    int s  = (m & 7) << 3;
    const float* src = enc + (long)m * 1024 + (k2 ^ s);
    f32x4 a = *(const f32x4*)src;
    f32x4 b = *(const f32x4*)(src + 4);
    s16x8 h;
    h[0] = (short)f2bf(a[0]); h[1] = (short)f2bf(a[1]); h[2] = (short)f2bf(a[2]); h[3] = (short)f2bf(a[3]);
    h[4] = (short)f2bf(b[0]); h[5] = (short)f2bf(b[1]); h[6] = (short)f2bf(b[2]); h[7] = (short)f2bf(b[3]);
    *(s16x8*)(dst + (long)m * 1024 + k2) = h;
}

// ---------------------------------------------------------------- K1: x = [pcv|emb] @ W_gx + b_gx
__global__ __launch_bounds__(512) void k_x(
    const int* __restrict__ dec_in, const float* __restrict__ pcv,
    const float* __restrict__ embt, const float* __restrict__ Wgx,
    const float* __restrict__ bgx, float* __restrict__ xbuf) {
    __shared__ float xs[1280];
    __shared__ float sred[8][64];
    int b = blockIdx.x, n0 = blockIdx.y * 64;     // grid (32,4)
    int tid = threadIdx.x, nl = tid & 63, ks = tid >> 6;   // 8 k-slices x 160
    long er = (long)dec_in[b] * EE;
    for (int i = tid; i < 1280; i += 512)
        xs[i] = (i < 1024) ? pcv[b * 1024 + i] : embt[er + i - 1024];
    __syncthreads();
    float acc = 0.f;
    for (int k = ks * 160; k < ks * 160 + 160; ++k)
        acc += xs[k] * Wgx[(long)k * EE + n0 + nl];
    sred[ks][nl] = acc;
    __syncthreads();
    if (tid < 64) {
        int n = n0 + tid;
        float s = bgx[n];
        #pragma unroll
        for (int i = 0; i < 8; i++) s += sred[i][tid];
        xbuf[b * EE + n] = s;
    }
}

// ---------------------------------------------------------------- K2: LSTM cell (fused k-split)
__global__ __launch_bounds__(512) void k_lstm(
    const float* __restrict__ xbuf, const float* __restrict__ h0,
    const float* __restrict__ c0, const float* __restrict__ Wih,
    const float* __restrict__ Whh, const float* __restrict__ bih,
    const float* __restrict__ bhh, float* __restrict__ h1o,
    float* __restrict__ c1o, float* __restrict__ dechat) {
    __shared__ float xs[768];
    __shared__ float sred[4][8][64];
    int b = blockIdx.x, d0 = blockIdx.y * 64;     // grid (32,8)
    int tid = threadIdx.x, dl = tid & 63, ks = tid >> 6;   // 8 k-slices x 96
    for (int i = tid; i < 768; i += 512)
        xs[i] = (i < 256) ? xbuf[b * 256 + i] : h0[b * 512 + i - 256];
    __syncthreads();
    float a0 = 0, a1 = 0, a2 = 0, a3 = 0;
    for (int k = ks * 96; k < ks * 96 + 96; ++k) {
        float xv = xs[k];
        const float* wr = (k < 256) ? (Wih + (long)k * 2048) : (Whh + (long)(k - 256) * 2048);
        a0 += xv * wr[d0 + dl];        a1 += xv * wr[512 + d0 + dl];
        a2 += xv * wr[1024 + d0 + dl]; a3 += xv * wr[1536 + d0 + dl];
    }
    sred[0][ks][dl] = a0; sred[1][ks][dl] = a1; sred[2][ks][dl] = a2; sred[3][ks][dl] = a3;
    __syncthreads();
    if (tid < 64) {
        int d = d0 + tid;
        float gi = bih[d] + bhh[d];
        float gf = bih[512 + d] + bhh[512 + d];
        float gg = bih[1024 + d] + bhh[1024 + d];
        float go = bih[1536 + d] + bhh[1536 + d];
        #pragma unroll
        for (int s = 0; s < 8; s++) {
            gi += sred[0][s][tid]; gf += sred[1][s][tid];
            gg += sred[2][s][tid]; go += sred[3][s][tid];
        }
        float c1 = sigmoidf_(gf) * c0[b * 512 + d] + sigmoidf_(gi) * tanh_fast(gg);
        float h1 = sigmoidf_(go) * tanh_fast(c1);
        h1o[b * 512 + d] = h1; c1o[b * 512 + d] = c1;
        dechat[b * 1024 + d] = h1; dechat[b * 1024 + 512 + d] = c1;
    }
}

// ---------------------------------------------------------------- K3: dec_feat = dec_hat @ W_s + b_s
__global__ __launch_bounds__(512) void k_decfeat(
    const float* __restrict__ dechat, const float* __restrict__ Ws,
    const float* __restrict__ bs, float* __restrict__ decfeat) {
    __shared__ float xs[1024];
    __shared__ float sred[8][64];
    int b = blockIdx.x, n0 = blockIdx.y * 64;     // grid (32,16)
    int tid = threadIdx.x, nl = tid & 63, ks = tid >> 6;   // 8 x 128
    for (int i = tid; i < 1024; i += 512) xs[i] = dechat[b * 1024 + i];
    __syncthreads();
    float acc = 0.f;
    for (int k = ks * 128; k < ks * 128 + 128; ++k)
        acc += xs[k] * Ws[(long)k * 1024 + n0 + nl];
    sred[ks][nl] = acc;
    __syncthreads();
    if (tid < 64) {
        int n = n0 + tid;
        float s = bs[n];
        #pragma unroll
        for (int i = 0; i < 8; i++) s += sred[i][tid];
        decfeat[b * 1024 + n] = s;
    }
}

// ---------------------------------------------------------------- K4: fused attention scores (R2 structure)
__global__ __launch_bounds__(512) void k_scores(
    const unsigned short* __restrict__ encswz, const unsigned short* __restrict__ whtswz,
    const float* __restrict__ decfeat, const float* __restrict__ cov,
    const float* __restrict__ Wc, const float* __restrict__ vvec,
    float* __restrict__ scorep) {
    __shared__ __align__(16) unsigned short As[128 * 64];   // 16 KB, linear, data pre-swizzled
    __shared__ __align__(16) unsigned short Bs[256 * 64];   // 32 KB
    __shared__ float sred[4][128];                          // total 50 KB -> 3 blocks/CU
    const int tid = threadIdx.x;
    const int lane = tid & 63, wave = tid >> 6;
    const int wid = __builtin_amdgcn_readfirstlane(wave);
    const int g = lane >> 4, c = lane & 15;
    const int wm = wave >> 2, wn = wave & 3;   // 2 x 4 waves over 128m x 256n

    const int bid = blockIdx.x;
    const int xcd = bid & 7, t = bid >> 3;
    const int mt = xcd * 32 + (t >> 2), nt = t & 3;
    const long m0 = (long)mt * 128;
    const int n0 = nt * 256;
    const int bblk = mt >> 3;                  // batch row

    const int arow = wid * 16 + (lane >> 3);
    const int axo  = (lane & 7) * 8;
    const int brow = wid * 32 + (lane >> 3);
    unsigned short* aBase = &As[wid * 1024];
    unsigned short* bBase = &Bs[wid * 2048];

    f32x4 acc[4][4];
    #pragma unroll
    for (int i = 0; i < 4; i++)
        #pragma unroll
        for (int j = 0; j < 4; j++) acc[i][j] = (f32x4){0.f, 0.f, 0.f, 0.f};

    const int sx = (c & 7) << 3;               // read-side swizzle

    for (int kt = 0; kt < 16; ++kt) {
        const int k0 = kt * 64;
        __syncthreads();
        gl16(encswz + (m0 + arow) * 1024 + k0 + axo,       aBase);
        gl16(encswz + (m0 + arow + 8) * 1024 + k0 + axo,   aBase + 512);
        gl16(whtswz + (long)(n0 + brow) * 1024 + k0 + axo,        bBase);
        gl16(whtswz + (long)(n0 + brow + 8) * 1024 + k0 + axo,    bBase + 512);
        gl16(whtswz + (long)(n0 + brow + 16) * 1024 + k0 + axo,   bBase + 1024);
        gl16(whtswz + (long)(n0 + brow + 24) * 1024 + k0 + axo,   bBase + 1536);
        __syncthreads();                       // drains vmcnt(0)
        #pragma unroll
        for (int kk = 0; kk < 2; ++kk) {
            const int kse = (kk * 32 + g * 8) ^ sx;
            s16x8 af[4], bfj[4];
            #pragma unroll
            for (int i = 0; i < 4; i++) af[i] = *(const s16x8*)&As[(wm * 64 + i * 16 + c) * 64 + kse];
            #pragma unroll
            for (int j = 0; j < 4; j++) bfj[j] = *(const s16x8*)&Bs[(wn * 64 + j * 16 + c) * 64 + kse];
            #pragma unroll
            for (int i = 0; i < 4; i++)
                #pragma unroll
                for (int j = 0; j < 4; j++)
                    acc[i][j] = __builtin_amdgcn_mfma_f32_16x16x32_bf16(af[i], bfj[j], acc[i][j], 0, 0, 0);
        }
    }
    float dfv[4], wcv[4], vvj[4];
    #pragma unroll
    for (int j = 0; j < 4; j++) {
        int col = n0 + wn * 64 + j * 16 + c;
        dfv[j] = decfeat[bblk * D2 + col];
        wcv[j] = Wc[col];
        vvj[j] = vvec[col];
    }
    float sAcc[4][4];
    #pragma unroll
    for (int i = 0; i < 4; i++) {
        #pragma unroll
        for (int r = 0; r < 4; r++) {
            const long m = m0 + wm * 64 + i * 16 + g * 4 + r;
            const float covm = cov[m];
            float su = 0.f;
            #pragma unroll
            for (int j = 0; j < 4; j++) {
                float e = acc[i][j][r] + dfv[j] + covm * wcv[j];
                su += tanh_fast(e) * vvj[j];
            }
            su += __shfl_xor(su, 1); su += __shfl_xor(su, 2);
            su += __shfl_xor(su, 4); su += __shfl_xor(su, 8);
            sAcc[i][r] = su;
        }
    }
    if (c == 0) {
        #pragma unroll
        for (int i = 0; i < 4; i++)
            #pragma unroll
            for (int r = 0; r < 4; r++)
                sred[wn][wm * 64 + i * 16 + g * 4 + r] = sAcc[i][r];
    }
    __syncthreads();
    if (tid < 128)
        scorep[(long)nt * MM + m0 + tid] = sred[0][tid] + sred[1][tid] + sred[2][tid] + sred[3][tid];
}

// ---------------------------------------------------------------- K5: softmax + mask renorm
__global__ void k_softmax(const float* __restrict__ scorep, const float* __restrict__ mask,
                          const float* __restrict__ cov, float* __restrict__ att,
                          float* __restrict__ covn) {
    int b = blockIdx.x, tid = threadIdx.x;  // 256 threads
    __shared__ float sm[8];
    float sv[4];
    float mx = -1e30f;
    #pragma unroll
    for (int i = 0; i < 4; i++) {
        long idx = (long)b * TT + tid + 256 * i;
        sv[i] = scorep[idx] + scorep[MM + idx] + scorep[2 * MM + idx] + scorep[3 * MM + idx];
        mx = fmaxf(mx, sv[i]);
    }
    for (int o = 32; o; o >>= 1) mx = fmaxf(mx, __shfl_xor(mx, o));
    if ((tid & 63) == 0) sm[tid >> 6] = mx;
    __syncthreads();
    mx = fmaxf(fmaxf(sm[0], sm[1]), fmaxf(sm[2], sm[3]));
    __syncthreads();
    float e[4]; float s = 0.f;
    #pragma unroll
    for (int i = 0; i < 4; i++) { e[i] = __expf(sv[i] - mx); s += e[i]; }
    for (int o = 32; o; o >>= 1) s += __shfl_xor(s, o);
    if ((tid & 63) == 0) sm[tid >> 6] = s;
    __syncthreads();
    s = sm[0] + sm[1] + sm[2] + sm[3];
    __syncthreads();
    float inv = 1.f / s;
    float am[4]; float s2 = 0.f;
    #pragma unroll
    for (int i = 0; i < 4; i++) { am[i] = e[i] * inv * mask[b * TT + tid + 256 * i]; s2 += am[i]; }
    for (int o = 32; o; o >>= 1) s2 += __shfl_xor(s2, o);
    if ((tid & 63) == 0) sm[tid >> 6] = s2;
    __syncthreads();
    s2 = sm[0] + sm[1] + sm[2] + sm[3];
    float inv2 = 1.f / s2;
    #pragma unroll
    for (int i = 0; i < 4; i++) {
        int t = tid + 256 * i;
        float a = am[i] * inv2;
        att[b * TT + t] = a;
        covn[b * TT + t] = cov[b * TT + t] + a;
    }
}

// ---------------------------------------------------------------- K6: context partials (bf16 enc) + reduce
__global__ void k_context(const unsigned short* __restrict__ encswz, const float* __restrict__ att,
                          float* __restrict__ part) {
    int b = blockIdx.x, tc = blockIdx.y;  // grid (32,16)
    int d4 = threadIdx.x;                 // 256 threads -> d = d4*4
    float a0 = 0, a1 = 0, a2 = 0, a3 = 0;
    const float* ab = att + b * TT;
    for (int t = tc * 64; t < tc * 64 + 64; ++t) {
        float a = ab[t];
        int sx = (t & 7) << 3;
        const unsigned short* ep = encswz + ((long)b * TT + t) * D2 + ((d4 * 4) ^ sx);
        s16x4 ev = *(const s16x4*)ep;
        a0 += a * bf2f((unsigned short)ev[0]); a1 += a * bf2f((unsigned short)ev[1]);
        a2 += a * bf2f((unsigned short)ev[2]); a3 += a * bf2f((unsigned short)ev[3]);
    }
    float* pp = part + (long)tc * BB * D2 + b * D2 + d4 * 4;
    pp[0] = a0; pp[1] = a1; pp[2] = a2; pp[3] = a3;
}

__global__ void k_ctxreduce(const float* __restrict__ part, float* __restrict__ ctx) {
    int i = blockIdx.x * 256 + threadIdx.x;  // 128 blocks
    float s = 0.f;
    #pragma unroll
    for (int p = 0; p < 16; p++) s += part[(long)p * BB * D2 + i];
    ctx[i] = s;
}

// ---------------------------------------------------------------- K7a: p_gen
__global__ void k_pgen(const float* __restrict__ ctx, const float* __restrict__ dechat,
                       const float* __restrict__ xbuf, const float* __restrict__ Wpg,
                       const float* __restrict__ bpg, float* __restrict__ pgen) {
    int b = blockIdx.x, tid = threadIdx.x;  // 256 threads
    __shared__ float sm[8];
    float acc = 0.f;
    for (int k = tid; k < D2; k += 256)
        acc += ctx[b * D2 + k] * Wpg[k] + dechat[b * D2 + k] * Wpg[D2 + k];
    acc += xbuf[b * EE + tid] * Wpg[2 * D2 + tid];
    for (int o = 32; o; o >>= 1) acc += __shfl_xor(acc, o);
    if ((tid & 63) == 0) sm[tid >> 6] = acc;
    __syncthreads();
    if (tid == 0) {
        float t = sm[0] + sm[1] + sm[2] + sm[3];
        pgen[b] = sigmoidf_(t + bpg[0]);
    }
}

// ---------------------------------------------------------------- K7b: hbf = bf16([h1|ctx] @ W_v1 + b_v1), [b][k]
__global__ __launch_bounds__(512) void k_hidden(
    const float* __restrict__ h1, const float* __restrict__ ctx,
    const float* __restrict__ Wv1, const float* __restrict__ bv1,
    unsigned short* __restrict__ hbf) {
    __shared__ float xs[1536];
    __shared__ float sred[8][64];
    int b = blockIdx.x, n0 = blockIdx.y * 64;   // grid (32,8)
    int tid = threadIdx.x, nl = tid & 63, ks = tid >> 6;   // 8 x 192
    for (int i = tid; i < 1536; i += 512)
        xs[i] = (i < 512) ? h1[b * 512 + i] : ctx[b * 1024 + i - 512];
    __syncthreads();
    float acc = 0.f;
    for (int k = ks * 192; k < ks * 192 + 192; ++k)
        acc += xs[k] * Wv1[(long)k * 512 + n0 + nl];
    sred[ks][nl] = acc;
    __syncthreads();
    if (tid < 64) {
        int n = n0 + tid;
        float s = bv1[n];
        #pragma unroll
        for (int i = 0; i < 8; i++) s += sred[i][tid];
        hbf[b * 512 + n] = f2bf(s);    // A-operand for MFMA logits
    }
}

// ---------------------------------------------------------------- K8: logits = hidden @ W_v2 + b_v2 (fused MFMA)
// 786 blocks x 256 thr (4 waves). Block -> 64 v-cols; per kt: stage Wv2 f32 [128k][64v]
// coalesced -> cvt bf16 -> LDS [v][k] (pitch 136, XOR-swizzled k) -> ds_read_b128 fragments.
__global__ __launch_bounds__(256) void k_logits(const unsigned short* __restrict__ hbf,
                                                const float* __restrict__ Wv2,
                                                const float* __restrict__ bv2,
                                                float* __restrict__ logits) {
    constexpr int PITCH = 136;   // bf16 elems per LDS row (128 + 8 -> +4 dwords mod 32)
    __shared__ __align__(16) unsigned short Bs[64 * PITCH];   // 17 KB
    const int tid = threadIdx.x;
    const int lane = tid & 63, wave = tid >> 6;
    const int g = lane >> 4, c = lane & 15;
    const int wm = wave >> 1, wn = wave & 1;     // 2 b-halves x 2 v-halves
    const long v0 = (long)blockIdx.x * 64;
    const bool tail = (v0 + 64 > VV);

    // staging map: vg = tid&15 -> 4 v cols; kr = tid>>4 -> 8 k rows
    const int vg = tid & 15, kr = tid >> 4;

    f32x4 acc[2];
    acc[0] = (f32x4){0.f, 0.f, 0.f, 0.f};
    acc[1] = (f32x4){0.f, 0.f, 0.f, 0.f};
    const int sxr = (c & 7) << 3;                // v&7 == c&7 for both v-subtiles

    for (int kt = 0; kt < 4; ++kt) {
        const int k0 = kt * 128;
        __syncthreads();
        #pragma unroll
        for (int pi = 0; pi < 4; ++pi) {
            const int ka = k0 + kr * 8 + pi * 2;
            f32x4 wa, wb;
            if (!tail) {
                wa = *(const f32x4*)&Wv2[(long)ka * VV + v0 + vg * 4];
                wb = *(const f32x4*)&Wv2[(long)(ka + 1) * VV + v0 + vg * 4];
            } else {
                #pragma unroll
                for (int j = 0; j < 4; j++) {
                    long v = v0 + vg * 4 + j;
                    long vs = (v < VV) ? v : (VV - 1);
                    wa[j] = Wv2[(long)ka * VV + vs];
                    wb[j] = Wv2[(long)(ka + 1) * VV + vs];
                }
            }
            #pragma unroll
            for (int j = 0; j < 4; j++) {
                int vl = vg * 4 + j;
                int ks = (kr * 8 + pi * 2) ^ ((vl & 7) << 3);
                unsigned int pack = (unsigned int)f2bf(wa[j]) | ((unsigned int)f2bf(wb[j]) << 16);
                *(unsigned int*)&Bs[vl * PITCH + ks] = pack;
            }
        }
        __syncthreads();
        #pragma unroll
        for (int kk = 0; kk < 4; ++kk) {
            const int koff = kk * 32 + g * 8;
            const int kse = koff ^ sxr;
            s16x8 af = *(const s16x8*)&hbf[(wm * 16 + c) * 512 + k0 + koff];
            s16x8 bf0 = *(const s16x8*)&Bs[(wn * 32 + c) * PITCH + kse];
            s16x8 bf1 = *(const s16x8*)&Bs[(wn * 32 + 16 + c) * PITCH + kse];
            acc[0] = __builtin_amdgcn_mfma_f32_16x16x32_bf16(af, bf0, acc[0], 0, 0, 0);
            acc[1] = __builtin_amdgcn_mfma_f32_16x16x32_bf16(af, bf1, acc[1], 0, 0, 0);
        }
    }
    // C layout: col=c (v), row=g*4+r (b)
    #pragma unroll
    for (int j = 0; j < 2; j++) {
        long v = v0 + wn * 32 + j * 16 + c;
        if (v < VV) {
            float bvv = bv2[v];
            #pragma unroll
            for (int r = 0; r < 4; r++) {
                int b = wm * 16 + g * 4 + r;
                logits[(long)b * VV + v] = acc[j][r] + bvv;
            }
        }
    }
}

// ---------------------------------------------------------------- K9: fused rowstats + vocab_final + scatter
__global__ __launch_bounds__(1024) void k_vocab_all(
    const float* __restrict__ logits, const float* __restrict__ pgen,
    const float* __restrict__ extraz, const float* __restrict__ att,
    const int* __restrict__ eiv, float* __restrict__ out0) {
    int b = blockIdx.x, tid = threadIdx.x;   // 32 blocks x 1024 thr
    __shared__ float sm[16];
    const float* lr = logits + (long)b * VV;
    float mx = -1e30f;
    for (int v = tid; v < VV; v += 1024) mx = fmaxf(mx, lr[v]);
    for (int o = 32; o; o >>= 1) mx = fmaxf(mx, __shfl_xor(mx, o));
    if ((tid & 63) == 0) sm[tid >> 6] = mx;
    __syncthreads();
    #pragma unroll
    for (int i = 0; i < 16; i++) mx = fmaxf(mx, sm[i]);
    __syncthreads();
    float s = 0.f;
    for (int v = tid; v < VV; v += 1024) s += __expf(lr[v] - mx);
    for (int o = 32; o; o >>= 1) s += __shfl_xor(s, o);
    if ((tid & 63) == 0) sm[tid >> 6] = s;
    __syncthreads();
    s = 0.f;
    #pragma unroll
    for (int i = 0; i < 16; i++) s += sm[i];
    float pg = pgen[b];
    float inv = pg / s;
    float* orow = out0 + (long)b * VE;
    for (int v = tid; v < VV; v += 1024) orow[v] = __expf(lr[v] - mx) * inv;
    if (tid < EXTRA) orow[VV + tid] = extraz[b * EXTRA + tid];
    __syncthreads();
    float a = (1.f - pg) * att[b * TT + tid];
    atomicAdd(orow + eiv[b * TT + tid], a);
}

// ================================================================ host
extern "C" void kernel_launch(void* const* d_in, const int* in_sizes, int n_in,
                              void* d_out, int out_size, void* d_ws, size_t ws_size,
                              hipStream_t stream) {
    const int*   dec_in = (const int*)d_in[0];
    const float* h0     = (const float*)d_in[1];
    const float* c0     = (const float*)d_in[2];
    const float* enc    = (const float*)d_in[3];
    const float* mask   = (const float*)d_in[4];
    const float* pcv    = (const float*)d_in[5];
    const float* cov    = (const float*)d_in[6];
    const float* extraz = (const float*)d_in[7];
    const int*   eiv    = (const int*)d_in[8];
    /* d_in[9] = step (unused, training path) */
    const float* embt   = (const float*)d_in[10];
    const float* Wgx    = (const float*)d_in[11];
    const float* bgx    = (const float*)d_in[12];
    const float* Wih    = (const float*)d_in[13];
    const float* Whh    = (const float*)d_in[14];
    const float* bih    = (const float*)d_in[15];
    const float* bhh    = (const float*)d_in[16];
    const float* Wh     = (const float*)d_in[17];
    const float* Wc     = (const float*)d_in[18];
    const float* Ws     = (const float*)d_in[19];
    const float* bs     = (const float*)d_in[20];
    const float* vv     = (const float*)d_in[21];
    const float* Wpg    = (const float*)d_in[22];
    const float* bpg    = (const float*)d_in[23];
    const float* Wv1    = (const float*)d_in[24];
    const float* bv1    = (const float*)d_in[25];
    const float* Wv2    = (const float*)d_in[26];
    const float* bv2    = (const float*)d_in[27];

    float* out = (float*)d_out;
    float* out_vd  = out;
    float* out_h1  = out + (long)BB * VE;
    float* out_c1  = out_h1 + BB * DD;
    float* out_ctx = out_c1 + BB * DD;
    float* out_att = out_ctx + BB * D2;
    float* out_cov = out_att + BB * TT;

    char* p = (char*)d_ws;
    unsigned short* whtswz = (unsigned short*)p; p += (size_t)D2 * D2 * 2;      // 2 MB
    float* xbuf    = (float*)p;  p += (size_t)BB * EE * 4;
    float* dechat  = (float*)p;  p += (size_t)BB * D2 * 4;
    float* decfeat = (float*)p;  p += (size_t)BB * D2 * 4;
    float* scorep  = (float*)p;  p += (size_t)4 * MM * 4;                        // 512 KB
    float* pgen    = (float*)p;  p += 256;
    unsigned short* hbf = (unsigned short*)p; p += (size_t)BB * DD * 2 + 256;    // 32 KB
    float* ctxpart = (float*)p;  p += (size_t)16 * BB * D2 * 4;                  // 2 MB
    float* logits  = (float*)p;  p += (size_t)BB * VV * 4;                       // 6.43 MB
    unsigned short* encswz = (unsigned short*)p; p += (size_t)MM * D2 * 2;       // 67.1 MB

    k_transpose_wh<<<dim3(32, 32), dim3(32, 8), 0, stream>>>(Wh, whtswz);
    k_enc2bf<<<16384, 256, 0, stream>>>(enc, encswz);
    k_x<<<dim3(BB, 4), 512, 0, stream>>>(dec_in, pcv, embt, Wgx, bgx, xbuf);
    k_lstm<<<dim3(BB, 8), 512, 0, stream>>>(xbuf, h0, c0, Wih, Whh, bih, bhh, out_h1, out_c1, dechat);
    k_decfeat<<<dim3(BB, 16), 512, 0, stream>>>(dechat, Ws, bs, decfeat);
    k_scores<<<1024, 512, 0, stream>>>(encswz, whtswz, decfeat, cov, Wc, vv, scorep);
    k_softmax<<<BB, 256, 0, stream>>>(scorep, mask, cov, out_att, out_cov);
    k_context<<<dim3(BB, 16), 256, 0, stream>>>(encswz, out_att, ctxpart);
    k_ctxreduce<<<(BB * D2) / 256, 256, 0, stream>>>(ctxpart, out_ctx);
    k_pgen<<<BB, 256, 0, stream>>>(out_ctx, dechat, xbuf, Wpg, bpg, pgen);
    k_hidden<<<dim3(BB, 8), 512, 0, stream>>>(out_h1, out_ctx, Wv1, bv1, hbf);
    k_logits<<<VPAD / 64, 256, 0, stream>>>(hbf, Wv2, bv2, logits);
    k_vocab_all<<<BB, 1024, 0, stream>>>(logits, pgen, extraz, out_att, eiv, out_vd);
}